// Round 6
// baseline (2007.105 us; speedup 1.0000x reference)
//
#include <hip/hip_runtime.h>
#include <hip/hip_bf16.h>

// ============================================================
// B=32, S=512, IN=3, H=64, D=128, NH=8, DH=16, L=4, C=5
// NSUB=10, MAX_CONSEC=50 -> SDE splits into 11 independent
// segments (state resets to enc at s % 51 == 0).
// Outputs (fp32): logits (160) then sde_features (32*512*64).
// R6 = R5 with __exp2f -> __builtin_amdgcn_exp2f (glibc name clash).
// ============================================================

typedef __attribute__((ext_vector_type(8))) short short8;
typedef __attribute__((ext_vector_type(4))) float f32x4;

// ---------------- ws layout (float element offsets) ----------------
static constexpr int OFF_TS      = 0;         // 49152
static constexpr int OFF_TIMES   = 49152;     // 16384
static constexpr int OFF_ENCW    = 65536;     // 192
static constexpr int OFF_ENCB    = 65728;     // 64
static constexpr int OFF_ENCG    = 65792;     // 64
static constexpr int OFF_ENCBETA = 65856;     // 64
static constexpr int OFF_DW1     = 65920;     // 8320 (65x128)
static constexpr int OFF_DB1     = 74240;     // 128
static constexpr int OFF_DW2     = 74368;     // 8192 (128x64)
static constexpr int OFF_DB2     = 82560;     // 64
static constexpr int OFF_DW3     = 82624;     // 4096 (64x64)
static constexpr int OFF_DB3     = 86720;     // 64
static constexpr int OFF_AW1     = 86784;     // 64
static constexpr int OFF_AB1     = 86848;     // 64
static constexpr int OFF_AW2     = 86912;     // 4096
static constexpr int OFF_AB2     = 91008;     // 64
static constexpr int OFF_BW1     = 91072;     // 64
static constexpr int OFF_BB1     = 91136;     // 64
static constexpr int OFF_BW2     = 91200;     // 4096
static constexpr int OFF_BB2     = 95296;     // 64
static constexpr int OFF_MD      = 95360;     // 1
static constexpr int OFF_INW     = 95424;     // 8192 (64x128)
static constexpr int OFF_INB     = 103616;    // 128
static constexpr int OFF_WQ      = 103744;    // 4*128*128
static constexpr int OFF_BQ      = 169280;    // 4*128
static constexpr int OFF_WK      = 169792;
static constexpr int OFF_BK      = 235328;
static constexpr int OFF_WV      = 235840;
static constexpr int OFF_BV      = 301376;
static constexpr int OFF_WO      = 301888;
static constexpr int OFF_BO      = 367424;
static constexpr int OFF_LN1G    = 367936;    // 4*128
static constexpr int OFF_LN1B    = 368448;
static constexpr int OFF_LN2G    = 368960;
static constexpr int OFF_LN2B    = 369472;
static constexpr int OFF_FW1     = 369984;    // 4*128*512
static constexpr int OFF_FB1     = 632128;    // 4*512
static constexpr int OFF_FW2     = 634176;    // 4*512*128
static constexpr int OFF_FB2     = 896320;    // 4*128
static constexpr int OFF_CW1     = 896832;    // 128*64
static constexpr int OFF_CB1     = 905024;    // 64
static constexpr int OFF_CW2     = 905088;    // 64*5 (pad)
static constexpr int OFF_CB2     = 905472;    // 5 (pad)
static constexpr int OFF_FLAG    = 905536;    // int flag: 1 = noise is bf16
// compute buffers
static constexpr int OFF_ENC     = 905600;    // 32*512*64 fp32
static constexpr int OFF_COEFA   = 3002752;   // 5110*64
static constexpr int OFF_COEFB   = 3329792;   // 5110*64
static constexpr int OFF_B1C     = 3656832;   // 5110*128
static constexpr int OFF_X       = 4310912;   // 16384*128 fp32 (residual master)
// bf16 buffers
static constexpr int OFF_XBF     = 6408064;   // 16384*128 bf16 (1048576 f)
static constexpr int OFF_QKVBF   = 7456640;   // 16384*384 bf16 (3145728 f)
static constexpr int OFF_OBF     = 10602368;  // 16384*128 bf16
static constexpr int OFF_HBF     = 11650944;  // 16384*512 bf16 (4194304 f)
static constexpr int OFF_SDEBF   = 15845248;  // 16384*64 bf16 (524288 f)
static constexpr int OFF_WQKVT   = 16369536;  // 4*384*128 bf16 (98304 f)
static constexpr int OFF_WOT     = 16467840;  // 4*128*128 bf16 (32768 f)
static constexpr int OFF_FW1T    = 16500608;  // 4*512*128 bf16 (131072 f)
static constexpr int OFF_FW2T    = 16631680;  // 4*128*512 bf16 (131072 f)
static constexpr int OFF_INWT    = 16762752;  // 128*64 bf16 (4096 f)
static constexpr int OFF_BQKV    = 16766848;  // 4*384 fp32
static constexpr int OFF_TMP     = 23185280;  // 16384*128 fp32
// total = 25282432 floats ~= 96.5 MiB

struct PtrPack { const void* p[45]; };

// ---------------- helpers ----------------
__device__ inline float wsum64(float v) {
#pragma unroll
  for (int off = 32; off > 0; off >>= 1) v += __shfl_xor(v, off, 64);
  return v;
}

__device__ inline float fast_tanh(float x) {
  x = fminf(fmaxf(x, -15.f), 15.f);
  float e = __expf(2.f * x);
  return (e - 1.f) / (e + 1.f);
}

// 5-instr tanh: 1 - 2/(exp2(2x*log2e)+1); saturates correctly at +-inf
__device__ inline float tanh5(float x) {
  float e = __builtin_amdgcn_exp2f(x * 2.88539008f);
  return 1.f - 2.f * __builtin_amdgcn_rcpf(e + 1.f);
}

__device__ inline float bfdec(unsigned short h) {
  return __uint_as_float(((unsigned)h) << 16);
}

// round-to-nearest-even f32 -> bf16 bits
__device__ inline short f2bf(float f) {
  unsigned u = __float_as_uint(f);
  return (short)((u + 0x7FFFu + ((u >> 16) & 1u)) >> 16);
}

// ---------------- ingest: convert all float inputs to f32 mirrors ----------------
__global__ __launch_bounds__(256) void ingest_kernel(PtrPack pk, float* __restrict__ W) {
  const int NE = 43;
  const int cnt[NE] = {49152,16384,192,64,64,64,8320,128,8192,64,4096,64,64,64,4096,64,
                       64,64,4096,64,1,8192,128,65536,512,65536,512,65536,512,65536,512,
                       512,512,512,512,262144,2048,262144,512,8192,64,320,5};
  const int src[NE] = {0,1,4,5,6,7,8,9,10,11,12,13,14,15,16,17,18,19,20,21,22,23,24,
                       25,26,27,28,29,30,31,32,33,34,35,36,37,38,39,40,41,42,43,44};
  const int dst[NE] = {OFF_TS,OFF_TIMES,OFF_ENCW,OFF_ENCB,OFF_ENCG,OFF_ENCBETA,OFF_DW1,
                       OFF_DB1,OFF_DW2,OFF_DB2,OFF_DW3,OFF_DB3,OFF_AW1,OFF_AB1,OFF_AW2,
                       OFF_AB2,OFF_BW1,OFF_BB1,OFF_BW2,OFF_BB2,OFF_MD,OFF_INW,OFF_INB,
                       OFF_WQ,OFF_BQ,OFF_WK,OFF_BK,OFF_WV,OFF_BV,OFF_WO,OFF_BO,
                       OFF_LN1G,OFF_LN1B,OFF_LN2G,OFF_LN2B,OFF_FW1,OFF_FB1,OFF_FW2,
                       OFF_FB2,OFF_CW1,OFF_CB1,OFF_CW2,OFF_CB2};
  const unsigned* eg = (const unsigned*)pk.p[6];     // enc_g (all ones)
  int gmode = (eg[0] == 0x3F803F80u) ? 1 : 0;

  __shared__ int isbf[NE];
  if (threadIdx.x < NE) {
    int k = threadIdx.x;
    int f = gmode;
    if (gmode) {
      const unsigned short* us = (const unsigned short*)pk.p[src[k]];
      int n = cnt[k] < 32 ? cnt[k] : 32;
      for (int i = 0; i < n; ++i) {
        unsigned short h = us[i];
        if (h & 0x7FFF) {
          float a = fabsf(bfdec(h));
          if (!(a > 1e-20f && a < 1e4f)) { f = 0; break; }
        }
      }
    }
    isbf[k] = f;
  }
  __syncthreads();

  int gid = blockIdx.x * 256 + threadIdx.x;
  int stride = gridDim.x * 256;
  if (gid == 0) {
    int nf = gmode;
    if (gmode) {
      const unsigned short* us = (const unsigned short*)pk.p[2];
      for (int i = 0; i < 32; ++i) {
        unsigned short h = us[i];
        if (h & 0x7FFF) {
          float a = fabsf(bfdec(h));
          if (!(a > 1e-20f && a < 1e4f)) { nf = 0; break; }
        }
      }
    }
    ((int*)W)[OFF_FLAG] = nf;
  }
  // per-array grid-stride copies (uniform k-loop, no per-element scan)
  for (int k = 0; k < NE; ++k) {
    int n = cnt[k];
    float* dp = W + dst[k];
    if (isbf[k]) {
      const unsigned short* us = (const unsigned short*)pk.p[src[k]];
      for (int e = gid; e < n; e += stride) dp[e] = bfdec(us[e]);
    } else {
      const float* fs = (const float*)pk.p[src[k]];
      for (int e = gid; e < n; e += stride) dp[e] = fs[e];
    }
  }
}

// ---------------- prep: transpose transformer weights to bf16 N-major ----------------
__global__ __launch_bounds__(256) void prep_kernel(float* __restrict__ W) {
  short* wqkvT = (short*)(W + OFF_WQKVT);
  short* woT   = (short*)(W + OFF_WOT);
  short* fw1T  = (short*)(W + OFF_FW1T);
  short* fw2T  = (short*)(W + OFF_FW2T);
  short* inwT  = (short*)(W + OFF_INWT);
  float* bqkv  = W + OFF_BQKV;
  int gid = blockIdx.x * 256 + threadIdx.x;
  int stride = gridDim.x * 256;
  for (int e = gid; e < 796160; e += stride) {
    if (e < 196608) {            // wqkvT[l][384][128]
      int l = e / 49152, r = e % 49152, n = r >> 7, k = r & 127;
      float v = (n < 128) ? W[OFF_WQ + l*16384 + k*128 + n]
              : (n < 256) ? W[OFF_WK + l*16384 + k*128 + (n - 128)]
                          : W[OFF_WV + l*16384 + k*128 + (n - 256)];
      wqkvT[e] = f2bf(v);
    } else if (e < 262144) {     // woT[l][128][128]
      int t = e - 196608; int l = t / 16384, r = t % 16384, n = r >> 7, k = r & 127;
      woT[t] = f2bf(W[OFF_WO + l*16384 + k*128 + n]);
    } else if (e < 524288) {     // fw1T[l][512][128]
      int t = e - 262144; int l = t / 65536, r = t % 65536, n = r >> 7, k = r & 127;
      fw1T[t] = f2bf(W[OFF_FW1 + l*65536 + k*512 + n]);
    } else if (e < 786432) {     // fw2T[l][128][512]
      int t = e - 524288; int l = t / 65536, r = t % 65536, n = r >> 9, k = r & 511;
      fw2T[t] = f2bf(W[OFF_FW2 + l*65536 + k*128 + n]);
    } else if (e < 794624) {     // inwT[128][64]
      int t = e - 786432; int n = t >> 6, k = t & 63;
      inwT[t] = f2bf(W[OFF_INW + k*128 + n]);
    } else {                     // bqkv[4][384] fp32
      int t = e - 794624; int l = t / 384, j = t % 384;
      bqkv[t] = (j < 128) ? W[OFF_BQ + l*128 + j]
              : (j < 256) ? W[OFF_BK + l*128 + (j - 128)]
                          : W[OFF_BV + l*128 + (j - 256)];
    }
  }
}

// ---------------- encoder: enc = relu(LN(ts @ enc_w + enc_b)) ----------------
__global__ __launch_bounds__(64) void encoder_kernel(float* __restrict__ W,
                                                     float* __restrict__ outf) {
  int row = blockIdx.x;        // b*512 + s
  int j = threadIdx.x;
  float t0 = W[OFF_TS + row*3 + 0];
  float t1 = W[OFF_TS + row*3 + 1];
  float t2 = W[OFF_TS + row*3 + 2];
  float v = W[OFF_ENCB + j] + t0 * W[OFF_ENCW + j] + t1 * W[OFF_ENCW + 64 + j]
          + t2 * W[OFF_ENCW + 128 + j];
  float mean = wsum64(v) * (1.f / 64.f);
  float d = v - mean;
  float var = wsum64(d * d) * (1.f / 64.f);
  float o = d * rsqrtf(var + 1e-5f) * W[OFF_ENCG + j] + W[OFF_ENCBETA + j];
  o = fmaxf(o, 0.f);
  W[OFF_ENC + row*64 + j] = o;
  int s = row & 511;
  if (s % 51 == 0) {           // reset positions: sde_features[:,s] = enc[:,s]
    ((short*)(W + OFF_SDEBF))[row*64 + j] = f2bf(o);
    outf[160 + row*64 + j] = o;
  }
}

// ---------------- precompute A(t), Bt(t), bias1(t) ----------------
__global__ __launch_bounds__(128) void precompute_kernel(float* __restrict__ W) {
  int bi = blockIdx.x;             // 0..5109
  int step = bi / 10, k = bi - step * 10;
  float t_prev = W[OFF_TIMES + step];
  float t_cur  = W[OFF_TIMES + step + 1];
  float h = (t_cur - t_prev) * 0.1f;
  float t = t_prev + (float)k * h;
  __shared__ float av[64], bv[64];
  int tid = threadIdx.x;
  if (tid < 64) av[tid] = fast_tanh(t * W[OFF_AW1 + tid] + W[OFF_AB1 + tid]);
  else { int j = tid - 64; bv[j] = fast_tanh(t * W[OFF_BW1 + j] + W[OFF_BB1 + j]); }
  __syncthreads();
  if (tid < 64) {
    float a = W[OFF_AB2 + tid];
    for (int i = 0; i < 64; ++i) a += av[i] * W[OFF_AW2 + i*64 + tid];
    W[OFF_COEFA + bi*64 + tid] = fmaxf(a, 0.f) + log1pf(__expf(-fabsf(a)));
  } else {
    int j = tid - 64;
    float a = W[OFF_BB2 + j];
    for (int i = 0; i < 64; ++i) a += bv[i] * W[OFF_BW2 + i*64 + j];
    W[OFF_COEFB + bi*64 + j] = fast_tanh(a);
  }
  W[OFF_B1C + bi*128 + tid] = t * W[OFF_DW1 + 64*128 + tid] + W[OFF_DB1 + tid];
}

// ---------------- SDE integrator: single wave per block, NO barriers ----------------
// 22 blocks x 64 threads. Wave owns 16 batch rows, full N of all stages.
// Intra-wave LDS ops are processed in order on CDNA -> no __syncthreads needed.
// MFMA 16x16x32 bf16 layouts: A[m=lane&15][k=q*8+j], B[k=q*8+j][n=lane&15],
// D[row=q*4+r][col=lane&15], q = lane>>4.
__global__ __launch_bounds__(64, 1) void sde_kernel(float* __restrict__ W,
                                                    const void* __restrict__ noise,
                                                    float* __restrict__ outf) {
  __shared__ short ybf[16 * 72];     // y bf16 [m][k] pitch 72
  __shared__ short h1bf[16 * 136];   // h1 [m][k] pitch 136
  __shared__ short h2bf[16 * 72];    // h2 [m][k] pitch 72

  const int lane = threadIdx.x;
  const int q = lane >> 4, lq = lane & 15;
  const int g = blockIdx.x >> 1;           // segment 0..10
  const int r0 = (blockIdx.x & 1) * 16;    // batch rows r0..r0+15

  const int nmode = ((const int*)W)[OFF_FLAG];
  const float md = fabsf(W[OFF_MD]);
  const unsigned short* nb16 = (const unsigned short*)noise;
  const float* nf32 = (const float*)noise;
  short* sdebf = (short*)(W + OFF_SDEBF);

  // ---- persistent weight B-frags in registers ----
  short8 B1f[2][8];   // [kt][nt] n = nt*16+lq
#pragma unroll
  for (int kt = 0; kt < 2; ++kt)
#pragma unroll
    for (int nt = 0; nt < 8; ++nt)
#pragma unroll
      for (int j = 0; j < 8; ++j)
        B1f[kt][nt][j] = f2bf(W[OFF_DW1 + (kt*32 + q*8 + j)*128 + nt*16 + lq]);
  short8 B2f[4][4];
#pragma unroll
  for (int kt = 0; kt < 4; ++kt)
#pragma unroll
    for (int nt = 0; nt < 4; ++nt)
#pragma unroll
      for (int j = 0; j < 8; ++j)
        B2f[kt][nt][j] = f2bf(W[OFF_DW2 + (kt*32 + q*8 + j)*64 + nt*16 + lq]);
  short8 B3f[2][4];
#pragma unroll
  for (int kt = 0; kt < 2; ++kt)
#pragma unroll
    for (int nt = 0; nt < 4; ++nt)
#pragma unroll
      for (int j = 0; j < 8; ++j)
        B3f[kt][nt][j] = f2bf(W[OFF_DW3 + (kt*32 + q*8 + j)*64 + nt*16 + lq]);
  float db2v[4], db3v[4];
#pragma unroll
  for (int nt = 0; nt < 4; ++nt) {
    db2v[nt] = W[OFF_DB2 + nt*16 + lq];
    db3v[nt] = W[OFF_DB3 + nt*16 + lq];
  }

  // ---- init y (fp32 master, D-layout: row q*4+r, col nt*16+lq) ----
  float yreg[4][4];
#pragma unroll
  for (int nt = 0; nt < 4; ++nt)
#pragma unroll
    for (int r = 0; r < 4; ++r) {
      yreg[nt][r] = W[OFF_ENC + ((r0 + q*4 + r)*512 + 51*g)*64 + nt*16 + lq];
      ybf[(q*4 + r)*72 + nt*16 + lq] = f2bf(yreg[nt][r]);
    }

  // ---- prefetch first substep's coefficients ----
  const int ci0 = 51*g*10;
  float b1c[8], ca[4], cb[4];
#pragma unroll
  for (int nt = 0; nt < 8; ++nt) b1c[nt] = W[OFF_B1C + ci0*128 + nt*16 + lq];
#pragma unroll
  for (int nt = 0; nt < 4; ++nt) {
    ca[nt] = W[OFF_COEFA + ci0*64 + nt*16 + lq];
    cb[nt] = W[OFF_COEFB + ci0*64 + nt*16 + lq];
  }

  const int nsteps = (g == 10) ? 1 : 50;
  for (int m = 0; m < nsteps; ++m) {
    const int istep = 51*g + m;
    const float t_prev = W[OFF_TIMES + istep];
    const float t_cur  = W[OFF_TIMES + istep + 1];
    const float hstep = (t_cur - t_prev) * 0.1f;
    const float sqh = sqrtf(hstep);
    for (int k = 0; k < 10; ++k) {
      const int ci = istep*10 + k;
      const int cin = (ci + 1 > 5109) ? 5109 : ci + 1;
      // prefetch NEXT substep's coefficients (in flight across this substep)
      float b1n[8], can[4], cbn[4];
#pragma unroll
      for (int nt = 0; nt < 8; ++nt) b1n[nt] = W[OFF_B1C + cin*128 + nt*16 + lq];
#pragma unroll
      for (int nt = 0; nt < 4; ++nt) {
        can[nt] = W[OFF_COEFA + cin*64 + nt*16 + lq];
        cbn[nt] = W[OFF_COEFB + cin*64 + nt*16 + lq];
      }
      // noise for this substep (used only in stage 3 -> latency hidden)
      float dwv[4][4];
      {
        const int nb = (((istep + 1)*10 + k)*32 + r0 + q*4)*64 + lq;
#pragma unroll
        for (int nt = 0; nt < 4; ++nt)
#pragma unroll
          for (int r = 0; r < 4; ++r) {
            int a = nb + r*64 + nt*16;
            dwv[nt][r] = nmode ? bfdec(nb16[a]) : nf32[a];
          }
      }
      // ---- stage 1: h1 = tanh(y @ w1 + bias1(t)) ----
      {
        short8 a0 = *(const short8*)&ybf[lq*72 + q*8];
        short8 a1 = *(const short8*)&ybf[lq*72 + 32 + q*8];
#pragma unroll
        for (int nt = 0; nt < 8; ++nt) {
          f32x4 c = {b1c[nt], b1c[nt], b1c[nt], b1c[nt]};
          c = __builtin_amdgcn_mfma_f32_16x16x32_bf16(a0, B1f[0][nt], c, 0, 0, 0);
          c = __builtin_amdgcn_mfma_f32_16x16x32_bf16(a1, B1f[1][nt], c, 0, 0, 0);
#pragma unroll
          for (int r = 0; r < 4; ++r)
            h1bf[(q*4 + r)*136 + nt*16 + lq] = f2bf(tanh5(c[r]));
        }
      }
      // ---- stage 2: h2 = tanh(h1 @ w2 + db2) ----
      {
        short8 h0 = *(const short8*)&h1bf[lq*136 + q*8];
        short8 h1 = *(const short8*)&h1bf[lq*136 + 32 + q*8];
        short8 h2 = *(const short8*)&h1bf[lq*136 + 64 + q*8];
        short8 h3 = *(const short8*)&h1bf[lq*136 + 96 + q*8];
#pragma unroll
        for (int nt = 0; nt < 4; ++nt) {
          f32x4 c = {db2v[nt], db2v[nt], db2v[nt], db2v[nt]};
          c = __builtin_amdgcn_mfma_f32_16x16x32_bf16(h0, B2f[0][nt], c, 0, 0, 0);
          c = __builtin_amdgcn_mfma_f32_16x16x32_bf16(h1, B2f[1][nt], c, 0, 0, 0);
          c = __builtin_amdgcn_mfma_f32_16x16x32_bf16(h2, B2f[2][nt], c, 0, 0, 0);
          c = __builtin_amdgcn_mfma_f32_16x16x32_bf16(h3, B2f[3][nt], c, 0, 0, 0);
#pragma unroll
          for (int r = 0; r < 4; ++r)
            h2bf[(q*4 + r)*72 + nt*16 + lq] = f2bf(tanh5(c[r]));
        }
      }
      // ---- stage 3: drift = h2 @ w3 + db3; Euler-Maruyama ----
      {
        short8 g0 = *(const short8*)&h2bf[lq*72 + q*8];
        short8 g1 = *(const short8*)&h2bf[lq*72 + 32 + q*8];
#pragma unroll
        for (int nt = 0; nt < 4; ++nt) {
          f32x4 d = {db3v[nt], db3v[nt], db3v[nt], db3v[nt]};
          d = __builtin_amdgcn_mfma_f32_16x16x32_bf16(g0, B3f[0][nt], d, 0, 0, 0);
          d = __builtin_amdgcn_mfma_f32_16x16x32_bf16(g1, B3f[1][nt], d, 0, 0, 0);
#pragma unroll
          for (int r = 0; r < 4; ++r) {
            float yv = yreg[nt][r];
            yv = yv + d[r]*hstep + (ca[nt] + cb[nt]*yv + md)*sqh*dwv[nt][r];
            yreg[nt][r] = yv;
            ybf[(q*4 + r)*72 + nt*16 + lq] = f2bf(yv);
          }
        }
      }
      // rotate prefetched coefficients
#pragma unroll
      for (int nt = 0; nt < 8; ++nt) b1c[nt] = b1n[nt];
#pragma unroll
      for (int nt = 0; nt < 4; ++nt) { ca[nt] = can[nt]; cb[nt] = cbn[nt]; }
    }
    // write sde_features[:, istep+1]
#pragma unroll
    for (int nt = 0; nt < 4; ++nt)
#pragma unroll
      for (int r = 0; r < 4; ++r) {
        const int gi = ((r0 + q*4 + r)*512 + (istep + 1))*64 + nt*16 + lq;
        sdebf[gi] = f2bf(yreg[nt][r]);
        outf[160 + gi] = yreg[nt][r];
      }
  }
}

// ---------------- bf16 MFMA GEMM (128x128 tile, 4 waves 2x2) ----------------
__global__ __launch_bounds__(256) void gemm_bf16_kernel(
    const short* __restrict__ A, const short* __restrict__ BT,
    const float* __restrict__ bias, float* __restrict__ Cf,
    short* __restrict__ Cb, int N, int K, int relu) {
  __shared__ short As[128 * 40];
  __shared__ short Bs[128 * 40];
  const int tid = threadIdx.x;
  const int w = tid >> 6, lane = tid & 63, q = lane >> 4, lq = lane & 15;
  const int wm = (w >> 1) * 64, wn = (w & 1) * 64;
  const int bm = blockIdx.x * 128, bn = blockIdx.y * 128;
  const int arow = tid >> 1, ah = (tid & 1) * 16;
  f32x4 acc[4][4];
#pragma unroll
  for (int i = 0; i < 4; ++i)
#pragma unroll
    for (int j = 0; j < 4; ++j) acc[i][j] = (f32x4){0.f, 0.f, 0.f, 0.f};

  for (int k0 = 0; k0 < K; k0 += 32) {
    short8 a0 = *(const short8*)&A[(bm + arow)*K + k0 + ah];
    short8 a1 = *(const short8*)&A[(bm + arow)*K + k0 + ah + 8];
    short8 b0 = *(const short8*)&BT[(bn + arow)*K + k0 + ah];
    short8 b1 = *(const short8*)&BT[(bn + arow)*K + k0 + ah + 8];
    __syncthreads();
    *(short8*)&As[arow*40 + ah]     = a0;
    *(short8*)&As[arow*40 + ah + 8] = a1;
    *(short8*)&Bs[arow*40 + ah]     = b0;
    *(short8*)&Bs[arow*40 + ah + 8] = b1;
    __syncthreads();
    short8 af[4], bf[4];
#pragma unroll
    for (int mi = 0; mi < 4; ++mi)
      af[mi] = *(const short8*)&As[(wm + mi*16 + lq)*40 + q*8];
#pragma unroll
    for (int ni = 0; ni < 4; ++ni)
      bf[ni] = *(const short8*)&Bs[(wn + ni*16 + lq)*40 + q*8];
#pragma unroll
    for (int mi = 0; mi < 4; ++mi)
#pragma unroll
      for (int ni = 0; ni < 4; ++ni)
        acc[mi][ni] = __builtin_amdgcn_mfma_f32_16x16x32_bf16(af[mi], bf[ni],
                                                              acc[mi][ni], 0, 0, 0);
  }
#pragma unroll
  for (int ni = 0; ni < 4; ++ni) {
    const int col = bn + wn + ni*16 + lq;
    const float bv = bias ? bias[col] : 0.f;
#pragma unroll
    for (int mi = 0; mi < 4; ++mi) {
#pragma unroll
      for (int r = 0; r < 4; ++r) {
        const int row = bm + wm + mi*16 + q*4 + r;
        float v = acc[mi][ni][r] + bv;
        if (relu) v = fmaxf(v, 0.f);
        if (Cf) Cf[row*N + col] = v;
        if (Cb) Cb[row*N + col] = f2bf(v);
      }
    }
  }
}

// ---------------- MFMA flash attention, DH=16 (K-dim zero-padded to 32) ----
// Block = (b, h, qtile of 64 rows); 4 waves x 16 q-rows. Full 512-score row
// kept in registers (no online softmax); P -> LDS -> A-frags for PV.
__global__ __launch_bounds__(256, 1) void attn_kernel(const short* __restrict__ QKV,
                                                      short* __restrict__ O) {
  __shared__ short Kt[512 * 20];    // K [key][d] pitch 20
  __shared__ short Vt[16 * 520];    // V^T [d][key] pitch 520
  __shared__ short Pb[4 * 16 * 520];// per-wave P [qrow][key] pitch 520
  const int blk = blockIdx.x;
  const int qt = blk & 7, h = (blk >> 3) & 7, b = blk >> 6;
  const int tid = threadIdx.x;
  const int w = tid >> 6, lane = tid & 63, q = lane >> 4, lq = lane & 15;

  // stage K (natural) and V (transposed)
#pragma unroll
  for (int kk = 0; kk < 2; ++kk) {
    const int key = tid + kk*256;
    const short* src = &QKV[(size_t)(b*512 + key)*384 + 128 + h*16];
    short8 k0 = *(const short8*)src;
    short8 k1 = *(const short8*)(src + 8);
    *(short8*)&Kt[key*20]     = k0;
    *(short8*)&Kt[key*20 + 8] = k1;
    short8 v0 = *(const short8*)(src + 128);
    short8 v1 = *(const short8*)(src + 136);
#pragma unroll
    for (int d = 0; d < 8; ++d) Vt[d*520 + key] = v0[d];
#pragma unroll
    for (int d = 0; d < 8; ++d) Vt[(8 + d)*520 + key] = v1[d];
  }
  __syncthreads();

  const int qrow0 = b*512 + qt*64 + w*16;   // wave's rows: qrow0 + m (m=lq)
  short8 aq = (short8){0,0,0,0,0,0,0,0};
  if (q < 2) aq = *(const short8*)&QKV[(size_t)(qrow0 + lq)*384 + h*16 + q*8];

  // scores: 32 k-tiles of 16 keys
  f32x4 acc[32];
#pragma unroll
  for (int t = 0; t < 32; ++t) {
    short8 bk = (short8){0,0,0,0,0,0,0,0};
    if (q < 2) bk = *(const short8*)&Kt[(t*16 + lq)*20 + q*8];
    f32x4 z = {0.f, 0.f, 0.f, 0.f};
    acc[t] = __builtin_amdgcn_mfma_f32_16x16x32_bf16(aq, bk, z, 0, 0, 0);
  }
  // softmax over 512 keys per q-row (rows q*4+r; keys 16t+lq)
  float mx[4] = {-1e30f, -1e30f, -1e30f, -1e30f};
#pragma unroll
  for (int t = 0; t < 32; ++t)
#pragma unroll
    for (int r = 0; r < 4; ++r) mx[r] = fmaxf(mx[r], acc[t][r]);
#pragma unroll
  for (int off = 1; off < 16; off <<= 1)
#pragma unroll
    for (int r = 0; r < 4; ++r) mx[r] = fmaxf(mx[r], __shfl_xor(mx[r], off, 16));
  const float cexp = 0.25f * 1.44269504f;   // scale/sqrt(DH) folded into exp2
  float ls[4] = {0.f, 0.f, 0.f, 0.f};
#pragma unroll
  for (int t = 0; t < 32; ++t)
#pragma unroll
    for (int r = 0; r < 4; ++r) {
      float p = __builtin_amdgcn_exp2f((acc[t][r] - mx[r]) * cexp);
      acc[t][r] = p;
      ls[r] += p;
    }
#pragma unroll
  for (int off = 1; off < 16; off <<= 1)
#pragma unroll
    for (int r = 0; r < 4; ++r) ls[r] += __shfl_xor(ls[r], off, 16);
  // P -> LDS (bf16 truncation; P in [0,1])
  short* Pw = &Pb[w * 8320];
#pragma unroll
  for (int t = 0; t < 32; ++t)
#pragma unroll
    for (int r = 0; r < 4; ++r)
      Pw[(q*4 + r)*520 + t*16 + lq] = (short)(__float_as_uint(acc[t][r]) >> 16);
  // PV: O[16x16] = P[16x512] @ V[512x16]  (intra-wave LDS -> in order, no barrier)
  f32x4 o0 = {0.f, 0.f, 0.f, 0.f}, o1 = {0.f, 0.f, 0.f, 0.f};
#pragma unroll
  for (int kt = 0; kt < 16; kt += 2) {
    short8 ap0 = *(const short8*)&Pw[lq*520 + kt*32 + q*8];
    short8 bv0 = *(const short8*)&Vt[lq*520 + kt*32 + q*8];
    short8 ap1 = *(const short8*)&Pw[lq*520 + (kt + 1)*32 + q*8];
    short8 bv1 = *(const short8*)&Vt[lq*520 + (kt + 1)*32 + q*8];
    o0 = __builtin_amdgcn_mfma_f32_16x16x32_bf16(ap0, bv0, o0, 0, 0, 0);
    o1 = __builtin_amdgcn_mfma_f32_16x16x32_bf16(ap1, bv1, o1, 0, 0, 0);
  }
#pragma unroll
  for (int r = 0; r < 4; ++r) {
    float ov = (o0[r] + o1[r]) * __builtin_amdgcn_rcpf(ls[r]);
    O[(size_t)(qrow0 + q*4 + r)*128 + h*16 + lq] = f2bf(ov);
  }
}

// ---------------- residual + LayerNorm (D=128): x fp32 + bf16 mirror --------
__global__ __launch_bounds__(128) void resln_kernel(float* __restrict__ x,
    const float* __restrict__ r, const float* __restrict__ g,
    const float* __restrict__ bta, short* __restrict__ xbf) {
  int row = blockIdx.x, j = threadIdx.x;
  int idx = row*128 + j;
  float v = x[idx] + r[idx];
  __shared__ float sm[2], sv[2];
  float s = wsum64(v);
  if ((j & 63) == 0) sm[j >> 6] = s;
  __syncthreads();
  float mean = (sm[0] + sm[1]) * (1.f / 128.f);
  float d = v - mean;
  float qq = wsum64(d * d);
  if ((j & 63) == 0) sv[j >> 6] = qq;
  __syncthreads();
  float var = (sv[0] + sv[1]) * (1.f / 128.f);
  float o = d * rsqrtf(var + 1e-5f) * g[j] + bta[j];
  x[idx] = o;
  xbf[idx] = f2bf(o);
}

// ---------------- mean-pool + 2-layer classifier ----------------
__global__ __launch_bounds__(128) void pool_cls_kernel(const float* __restrict__ W,
                                                       float* __restrict__ outf) {
  int b = blockIdx.x, j = threadIdx.x;
  float s = 0.f;
  for (int ss = 0; ss < 512; ++ss) s += W[OFF_X + ((b*512 + ss)*128) + j];
  __shared__ float pooled[128];
  __shared__ float hid[64];
  pooled[j] = s * (1.f / 512.f);
  __syncthreads();
  if (j < 64) {
    float a = W[OFF_CB1 + j];
    for (int i = 0; i < 128; ++i) a += pooled[i] * W[OFF_CW1 + i*64 + j];
    hid[j] = fmaxf(a, 0.f);
  }
  __syncthreads();
  if (j < 5) {
    float a = W[OFF_CB2 + j];
    for (int i = 0; i < 64; ++i) a += hid[i] * W[OFF_CW2 + i*5 + j];
    outf[b*5 + j] = a;
  }
}

// ---------------- launch ----------------
extern "C" void kernel_launch(void* const* d_in, const int* in_sizes, int n_in,
                              void* d_out, int out_size, void* d_ws, size_t ws_size,
                              hipStream_t stream) {
  (void)in_sizes; (void)out_size; (void)ws_size;
  float* W = reinterpret_cast<float*>(d_ws);
  float* outf = reinterpret_cast<float*>(d_out);
  short* sdebf = (short*)(W + OFF_SDEBF);
  short* xbf   = (short*)(W + OFF_XBF);
  short* qkvbf = (short*)(W + OFF_QKVBF);
  short* obf   = (short*)(W + OFF_OBF);
  short* hbf   = (short*)(W + OFF_HBF);
  PtrPack pk;
  for (int i = 0; i < 45 && i < n_in; ++i) pk.p[i] = d_in[i];

  ingest_kernel<<<512, 256, 0, stream>>>(pk, W);
  prep_kernel<<<512, 256, 0, stream>>>(W);
  encoder_kernel<<<16384, 64, 0, stream>>>(W, outf);
  precompute_kernel<<<5110, 128, 0, stream>>>(W);
  sde_kernel<<<22, 64, 0, stream>>>(W, d_in[2], outf);

  // x = sde_features @ in_w + in_b  (fp32 master + bf16 mirror)
  gemm_bf16_kernel<<<dim3(128, 1), 256, 0, stream>>>(sdebf, (short*)(W + OFF_INWT),
      W + OFF_INB, W + OFF_X, xbf, 128, 64, 0);
  for (int l = 0; l < 4; ++l) {
    gemm_bf16_kernel<<<dim3(128, 3), 256, 0, stream>>>(xbf,
        (short*)(W + OFF_WQKVT) + l*49152, W + OFF_BQKV + l*384,
        (float*)nullptr, qkvbf, 384, 128, 0);
    attn_kernel<<<2048, 256, 0, stream>>>(qkvbf, obf);
    gemm_bf16_kernel<<<dim3(128, 1), 256, 0, stream>>>(obf,
        (short*)(W + OFF_WOT) + l*16384, W + OFF_BO + l*128,
        W + OFF_TMP, (short*)nullptr, 128, 128, 0);
    resln_kernel<<<16384, 128, 0, stream>>>(W + OFF_X, W + OFF_TMP,
        W + OFF_LN1G + l*128, W + OFF_LN1B + l*128, xbf);
    gemm_bf16_kernel<<<dim3(128, 4), 256, 0, stream>>>(xbf,
        (short*)(W + OFF_FW1T) + l*65536, W + OFF_FB1 + l*512,
        (float*)nullptr, hbf, 512, 128, 1);
    gemm_bf16_kernel<<<dim3(128, 1), 256, 0, stream>>>(hbf,
        (short*)(W + OFF_FW2T) + l*65536, W + OFF_FB2 + l*128,
        W + OFF_TMP, (short*)nullptr, 128, 512, 0);
    resln_kernel<<<16384, 128, 0, stream>>>(W + OFF_X, W + OFF_TMP,
        W + OFF_LN2G + l*128, W + OFF_LN2B + l*128, xbf);
  }
  pool_cls_kernel<<<32, 128, 0, stream>>>(W, outf);
}

// Round 7
// 1170.314 us; speedup vs baseline: 1.7150x; 1.7150x over previous
//
#include <hip/hip_runtime.h>
#include <hip/hip_bf16.h>

// ============================================================
// B=32, S=512, IN=3, H=64, D=128, NH=8, DH=16, L=4, C=5
// NSUB=10, MAX_CONSEC=50 -> SDE splits into 11 independent
// segments (state resets to enc at s % 51 == 0).
// Outputs (fp32): logits (160) then sde_features (32*512*64).
// R7: SDE back to 4-wave N-split (R3) + lgkmcnt-only barriers +
// coef/noise prefetch; residual+LN fused into N=128 GEMMs.
// ============================================================

typedef __attribute__((ext_vector_type(8))) short short8;
typedef __attribute__((ext_vector_type(4))) float f32x4;

// ---------------- ws layout (float element offsets) ----------------
static constexpr int OFF_TS      = 0;         // 49152
static constexpr int OFF_TIMES   = 49152;     // 16384
static constexpr int OFF_ENCW    = 65536;     // 192
static constexpr int OFF_ENCB    = 65728;     // 64
static constexpr int OFF_ENCG    = 65792;     // 64
static constexpr int OFF_ENCBETA = 65856;     // 64
static constexpr int OFF_DW1     = 65920;     // 8320 (65x128)
static constexpr int OFF_DB1     = 74240;     // 128
static constexpr int OFF_DW2     = 74368;     // 8192 (128x64)
static constexpr int OFF_DB2     = 82560;     // 64
static constexpr int OFF_DW3     = 82624;     // 4096 (64x64)
static constexpr int OFF_DB3     = 86720;     // 64
static constexpr int OFF_AW1     = 86784;     // 64
static constexpr int OFF_AB1     = 86848;     // 64
static constexpr int OFF_AW2     = 86912;     // 4096
static constexpr int OFF_AB2     = 91008;     // 64
static constexpr int OFF_BW1     = 91072;     // 64
static constexpr int OFF_BB1     = 91136;     // 64
static constexpr int OFF_BW2     = 91200;     // 4096
static constexpr int OFF_BB2     = 95296;     // 64
static constexpr int OFF_MD      = 95360;     // 1
static constexpr int OFF_INW     = 95424;     // 8192 (64x128)
static constexpr int OFF_INB     = 103616;    // 128
static constexpr int OFF_WQ      = 103744;    // 4*128*128
static constexpr int OFF_BQ      = 169280;    // 4*128
static constexpr int OFF_WK      = 169792;
static constexpr int OFF_BK      = 235328;
static constexpr int OFF_WV      = 235840;
static constexpr int OFF_BV      = 301376;
static constexpr int OFF_WO      = 301888;
static constexpr int OFF_BO      = 367424;
static constexpr int OFF_LN1G    = 367936;    // 4*128
static constexpr int OFF_LN1B    = 368448;
static constexpr int OFF_LN2G    = 368960;
static constexpr int OFF_LN2B    = 369472;
static constexpr int OFF_FW1     = 369984;    // 4*128*512
static constexpr int OFF_FB1     = 632128;    // 4*512
static constexpr int OFF_FW2     = 634176;    // 4*512*128
static constexpr int OFF_FB2     = 896320;    // 4*128
static constexpr int OFF_CW1     = 896832;    // 128*64
static constexpr int OFF_CB1     = 905024;    // 64
static constexpr int OFF_CW2     = 905088;    // 64*5 (pad)
static constexpr int OFF_CB2     = 905472;    // 5 (pad)
static constexpr int OFF_FLAG    = 905536;    // int flag: 1 = noise is bf16
// compute buffers
static constexpr int OFF_ENC     = 905600;    // 32*512*64 fp32
static constexpr int OFF_COEFA   = 3002752;   // 5110*64
static constexpr int OFF_COEFB   = 3329792;   // 5110*64
static constexpr int OFF_B1C     = 3656832;   // 5110*128
static constexpr int OFF_X       = 4310912;   // 16384*128 fp32 (residual master)
// bf16 buffers
static constexpr int OFF_XBF     = 6408064;   // 16384*128 bf16 (1048576 f)
static constexpr int OFF_QKVBF   = 7456640;   // 16384*384 bf16 (3145728 f)
static constexpr int OFF_OBF     = 10602368;  // 16384*128 bf16
static constexpr int OFF_HBF     = 11650944;  // 16384*512 bf16 (4194304 f)
static constexpr int OFF_SDEBF   = 15845248;  // 16384*64 bf16 (524288 f)
static constexpr int OFF_WQKVT   = 16369536;  // 4*384*128 bf16 (98304 f)
static constexpr int OFF_WOT     = 16467840;  // 4*128*128 bf16 (32768 f)
static constexpr int OFF_FW1T    = 16500608;  // 4*512*128 bf16 (131072 f)
static constexpr int OFF_FW2T    = 16631680;  // 4*128*512 bf16 (131072 f)
static constexpr int OFF_INWT    = 16762752;  // 128*64 bf16 (4096 f)
static constexpr int OFF_BQKV    = 16766848;  // 4*384 fp32
static constexpr int OFF_TMP     = 23185280;  // 16384*128 fp32 (unused now)
// total = 25282432 floats ~= 96.5 MiB

struct PtrPack { const void* p[45]; };

// ---------------- helpers ----------------
__device__ inline float wsum64(float v) {
#pragma unroll
  for (int off = 32; off > 0; off >>= 1) v += __shfl_xor(v, off, 64);
  return v;
}

__device__ inline float fast_tanh(float x) {
  x = fminf(fmaxf(x, -15.f), 15.f);
  float e = __expf(2.f * x);
  return (e - 1.f) / (e + 1.f);
}

// 5-instr tanh: 1 - 2/(exp2(2x*log2e)+1); saturates correctly at +-inf
__device__ inline float tanh5(float x) {
  float e = __builtin_amdgcn_exp2f(x * 2.88539008f);
  return 1.f - 2.f * __builtin_amdgcn_rcpf(e + 1.f);
}

__device__ inline float bfdec(unsigned short h) {
  return __uint_as_float(((unsigned)h) << 16);
}

// round-to-nearest-even f32 -> bf16 bits
__device__ inline short f2bf(float f) {
  unsigned u = __float_as_uint(f);
  return (short)((u + 0x7FFFu + ((u >> 16) & 1u)) >> 16);
}

// workgroup barrier that drains ONLY LDS ops (no vmcnt drain -> global
// prefetches stay in flight across it)
__device__ inline void lds_barrier() {
  asm volatile("s_waitcnt lgkmcnt(0)\ns_barrier" ::: "memory");
}

// ---------------- ingest: convert all float inputs to f32 mirrors ----------------
__global__ __launch_bounds__(256) void ingest_kernel(PtrPack pk, float* __restrict__ W) {
  const int NE = 43;
  const int cnt[NE] = {49152,16384,192,64,64,64,8320,128,8192,64,4096,64,64,64,4096,64,
                       64,64,4096,64,1,8192,128,65536,512,65536,512,65536,512,65536,512,
                       512,512,512,512,262144,2048,262144,512,8192,64,320,5};
  const int src[NE] = {0,1,4,5,6,7,8,9,10,11,12,13,14,15,16,17,18,19,20,21,22,23,24,
                       25,26,27,28,29,30,31,32,33,34,35,36,37,38,39,40,41,42,43,44};
  const int dst[NE] = {OFF_TS,OFF_TIMES,OFF_ENCW,OFF_ENCB,OFF_ENCG,OFF_ENCBETA,OFF_DW1,
                       OFF_DB1,OFF_DW2,OFF_DB2,OFF_DW3,OFF_DB3,OFF_AW1,OFF_AB1,OFF_AW2,
                       OFF_AB2,OFF_BW1,OFF_BB1,OFF_BW2,OFF_BB2,OFF_MD,OFF_INW,OFF_INB,
                       OFF_WQ,OFF_BQ,OFF_WK,OFF_BK,OFF_WV,OFF_BV,OFF_WO,OFF_BO,
                       OFF_LN1G,OFF_LN1B,OFF_LN2G,OFF_LN2B,OFF_FW1,OFF_FB1,OFF_FW2,
                       OFF_FB2,OFF_CW1,OFF_CB1,OFF_CW2,OFF_CB2};
  const unsigned* eg = (const unsigned*)pk.p[6];     // enc_g (all ones)
  int gmode = (eg[0] == 0x3F803F80u) ? 1 : 0;

  __shared__ int isbf[NE];
  if (threadIdx.x < NE) {
    int k = threadIdx.x;
    int f = gmode;
    if (gmode) {
      const unsigned short* us = (const unsigned short*)pk.p[src[k]];
      int n = cnt[k] < 32 ? cnt[k] : 32;
      for (int i = 0; i < n; ++i) {
        unsigned short h = us[i];
        if (h & 0x7FFF) {
          float a = fabsf(bfdec(h));
          if (!(a > 1e-20f && a < 1e4f)) { f = 0; break; }
        }
      }
    }
    isbf[k] = f;
  }
  __syncthreads();

  int gid = blockIdx.x * 256 + threadIdx.x;
  int stride = gridDim.x * 256;
  if (gid == 0) {
    int nf = gmode;
    if (gmode) {
      const unsigned short* us = (const unsigned short*)pk.p[2];
      for (int i = 0; i < 32; ++i) {
        unsigned short h = us[i];
        if (h & 0x7FFF) {
          float a = fabsf(bfdec(h));
          if (!(a > 1e-20f && a < 1e4f)) { nf = 0; break; }
        }
      }
    }
    ((int*)W)[OFF_FLAG] = nf;
  }
  // per-array grid-stride copies
  for (int k = 0; k < NE; ++k) {
    int n = cnt[k];
    float* dp = W + dst[k];
    if (isbf[k]) {
      const unsigned short* us = (const unsigned short*)pk.p[src[k]];
      for (int e = gid; e < n; e += stride) dp[e] = bfdec(us[e]);
    } else {
      const float* fs = (const float*)pk.p[src[k]];
      for (int e = gid; e < n; e += stride) dp[e] = fs[e];
    }
  }
}

// ---------------- prep: transpose transformer weights to bf16 N-major ----------------
__global__ __launch_bounds__(256) void prep_kernel(float* __restrict__ W) {
  short* wqkvT = (short*)(W + OFF_WQKVT);
  short* woT   = (short*)(W + OFF_WOT);
  short* fw1T  = (short*)(W + OFF_FW1T);
  short* fw2T  = (short*)(W + OFF_FW2T);
  short* inwT  = (short*)(W + OFF_INWT);
  float* bqkv  = W + OFF_BQKV;
  int gid = blockIdx.x * 256 + threadIdx.x;
  int stride = gridDim.x * 256;
  for (int e = gid; e < 796160; e += stride) {
    if (e < 196608) {            // wqkvT[l][384][128]
      int l = e / 49152, r = e % 49152, n = r >> 7, k = r & 127;
      float v = (n < 128) ? W[OFF_WQ + l*16384 + k*128 + n]
              : (n < 256) ? W[OFF_WK + l*16384 + k*128 + (n - 128)]
                          : W[OFF_WV + l*16384 + k*128 + (n - 256)];
      wqkvT[e] = f2bf(v);
    } else if (e < 262144) {     // woT[l][128][128]
      int t = e - 196608; int l = t / 16384, r = t % 16384, n = r >> 7, k = r & 127;
      woT[t] = f2bf(W[OFF_WO + l*16384 + k*128 + n]);
    } else if (e < 524288) {     // fw1T[l][512][128]
      int t = e - 262144; int l = t / 65536, r = t % 65536, n = r >> 7, k = r & 127;
      fw1T[t] = f2bf(W[OFF_FW1 + l*65536 + k*512 + n]);
    } else if (e < 786432) {     // fw2T[l][128][512]
      int t = e - 524288; int l = t / 65536, r = t % 65536, n = r >> 9, k = r & 511;
      fw2T[t] = f2bf(W[OFF_FW2 + l*65536 + k*128 + n]);
    } else if (e < 794624) {     // inwT[128][64]
      int t = e - 786432; int n = t >> 6, k = t & 63;
      inwT[t] = f2bf(W[OFF_INW + k*128 + n]);
    } else {                     // bqkv[4][384] fp32
      int t = e - 794624; int l = t / 384, j = t % 384;
      bqkv[t] = (j < 128) ? W[OFF_BQ + l*128 + j]
              : (j < 256) ? W[OFF_BK + l*128 + (j - 128)]
                          : W[OFF_BV + l*128 + (j - 256)];
    }
  }
}

// ---------------- encoder: enc = relu(LN(ts @ enc_w + enc_b)) ----------------
__global__ __launch_bounds__(64) void encoder_kernel(float* __restrict__ W,
                                                     float* __restrict__ outf) {
  int row = blockIdx.x;        // b*512 + s
  int j = threadIdx.x;
  float t0 = W[OFF_TS + row*3 + 0];
  float t1 = W[OFF_TS + row*3 + 1];
  float t2 = W[OFF_TS + row*3 + 2];
  float v = W[OFF_ENCB + j] + t0 * W[OFF_ENCW + j] + t1 * W[OFF_ENCW + 64 + j]
          + t2 * W[OFF_ENCW + 128 + j];
  float mean = wsum64(v) * (1.f / 64.f);
  float d = v - mean;
  float var = wsum64(d * d) * (1.f / 64.f);
  float o = d * rsqrtf(var + 1e-5f) * W[OFF_ENCG + j] + W[OFF_ENCBETA + j];
  o = fmaxf(o, 0.f);
  W[OFF_ENC + row*64 + j] = o;
  int s = row & 511;
  if (s % 51 == 0) {           // reset positions: sde_features[:,s] = enc[:,s]
    ((short*)(W + OFF_SDEBF))[row*64 + j] = f2bf(o);
    outf[160 + row*64 + j] = o;
  }
}

// ---------------- precompute A(t), Bt(t), bias1(t) ----------------
__global__ __launch_bounds__(128) void precompute_kernel(float* __restrict__ W) {
  int bi = blockIdx.x;             // 0..5109
  int step = bi / 10, k = bi - step * 10;
  float t_prev = W[OFF_TIMES + step];
  float t_cur  = W[OFF_TIMES + step + 1];
  float h = (t_cur - t_prev) * 0.1f;
  float t = t_prev + (float)k * h;
  __shared__ float av[64], bv[64];
  int tid = threadIdx.x;
  if (tid < 64) av[tid] = fast_tanh(t * W[OFF_AW1 + tid] + W[OFF_AB1 + tid]);
  else { int j = tid - 64; bv[j] = fast_tanh(t * W[OFF_BW1 + j] + W[OFF_BB1 + j]); }
  __syncthreads();
  if (tid < 64) {
    float a = W[OFF_AB2 + tid];
    for (int i = 0; i < 64; ++i) a += av[i] * W[OFF_AW2 + i*64 + tid];
    W[OFF_COEFA + bi*64 + tid] = fmaxf(a, 0.f) + log1pf(__expf(-fabsf(a)));
  } else {
    int j = tid - 64;
    float a = W[OFF_BB2 + j];
    for (int i = 0; i < 64; ++i) a += bv[i] * W[OFF_BW2 + i*64 + j];
    W[OFF_COEFB + bi*64 + j] = fast_tanh(a);
  }
  W[OFF_B1C + bi*128 + tid] = t * W[OFF_DW1 + 64*128 + tid] + W[OFF_DB1 + tid];
}

// ---------------- SDE integrator: 22 blocks, 4 waves split N ----------------
// R3 structure (parallel chains on 4 SIMDs) + lgkmcnt-only barriers so the
// coef/noise global prefetches stay in flight across all 3 stage barriers.
// MFMA 16x16x32 bf16 layouts: A[m=lane&15][k=q*8+j], B[k=q*8+j][n=lane&15],
// D[row=q*4+r][col=lane&15], q = lane>>4.
__global__ __launch_bounds__(256, 1) void sde_kernel(float* __restrict__ W,
                                                     const void* __restrict__ noise,
                                                     float* __restrict__ outf) {
  __shared__ short ybf[16 * 72];     // y bf16 [m][k] pitch 72
  __shared__ short h1bf[16 * 136];   // h1 [m][k] pitch 136
  __shared__ short h2bf[16 * 72];    // h2 [m][k] pitch 72

  const int tid = threadIdx.x;
  const int w   = tid >> 6;          // wave 0..3
  const int lane = tid & 63;
  const int q   = lane >> 4;         // quad
  const int lq  = lane & 15;
  const int g   = blockIdx.x >> 1;          // segment 0..10
  const int r0  = (blockIdx.x & 1) * 16;    // batch rows r0..r0+15

  const int nmode = ((const int*)W)[OFF_FLAG];
  const float md = fabsf(W[OFF_MD]);
  const unsigned short* nb16 = (const unsigned short*)noise;
  const float* nf32 = (const float*)noise;
  short* sdebf = (short*)(W + OFF_SDEBF);

  // ---- persistent weight B-frags in registers ----
  const int ncol = w*16 + lq;        // this wave's y/h2/drift column
  short8 B1f[2][2];                  // [kt][ct]; h1 cols n = w*32 + ct*16 + lq
#pragma unroll
  for (int kt = 0; kt < 2; ++kt)
#pragma unroll
    for (int ct = 0; ct < 2; ++ct)
#pragma unroll
      for (int j = 0; j < 8; ++j)
        B1f[kt][ct][j] = f2bf(W[OFF_DW1 + (kt*32 + q*8 + j)*128 + w*32 + ct*16 + lq]);
  short8 B2f[4];
#pragma unroll
  for (int kt = 0; kt < 4; ++kt)
#pragma unroll
    for (int j = 0; j < 8; ++j)
      B2f[kt][j] = f2bf(W[OFF_DW2 + (kt*32 + q*8 + j)*64 + ncol]);
  short8 B3f[2];
#pragma unroll
  for (int kt = 0; kt < 2; ++kt)
#pragma unroll
    for (int j = 0; j < 8; ++j)
      B3f[kt][j] = f2bf(W[OFF_DW3 + (kt*32 + q*8 + j)*64 + ncol]);
  const float db2v = W[OFF_DB2 + ncol];
  const float db3v = W[OFF_DB3 + ncol];

  // ---- init y (fp32 master in registers, D-layout) ----
  float yreg[4];
#pragma unroll
  for (int r = 0; r < 4; ++r) {
    yreg[r] = W[OFF_ENC + ((r0 + q*4 + r)*512 + 51*g)*64 + ncol];
    ybf[(q*4 + r)*72 + ncol] = f2bf(yreg[r]);
  }

  // ---- prefetch first substep's coefficients ----
  const int ci0 = 51*g*10;
  float bias_a = W[OFF_B1C + ci0*128 + w*32 + lq];
  float bias_b = W[OFF_B1C + ci0*128 + w*32 + 16 + lq];
  float ca = W[OFF_COEFA + ci0*64 + ncol];
  float cb = W[OFF_COEFB + ci0*64 + ncol];

  const int nsteps = (g == 10) ? 1 : 50;
  for (int m = 0; m < nsteps; ++m) {
    const int istep = 51*g + m;
    const float t_prev = W[OFF_TIMES + istep];
    const float t_cur  = W[OFF_TIMES + istep + 1];
    const float hstep = (t_cur - t_prev) * 0.1f;
    const float sqh = sqrtf(hstep);
    for (int k = 0; k < 10; ++k) {
      const int ci = istep*10 + k;
      const int cin = (ci + 1 > 5109) ? 5109 : ci + 1;
      // prefetch NEXT substep's coefficients + this substep's noise.
      // These are global loads; lds_barrier does NOT drain them — they
      // complete at first use (stage 3 / next substep).
      float b1na = W[OFF_B1C + cin*128 + w*32 + lq];
      float b1nb = W[OFF_B1C + cin*128 + w*32 + 16 + lq];
      float can = W[OFF_COEFA + cin*64 + ncol];
      float cbn = W[OFF_COEFB + cin*64 + ncol];
      float dwv[4];
      {
        const int nb = (((istep + 1)*10 + k)*32 + r0 + q*4)*64 + ncol;
#pragma unroll
        for (int r = 0; r < 4; ++r)
          dwv[r] = nmode ? bfdec(nb16[nb + r*64]) : nf32[nb + r*64];
      }
      lds_barrier();   // ybf (prev stage3 / init) visible
      // ---- stage 1: h1 = tanh(y @ w1 + bias1(t)) ----
      {
        short8 a0 = *(const short8*)&ybf[lq*72 + q*8];
        short8 a1 = *(const short8*)&ybf[lq*72 + 32 + q*8];
        f32x4 c0 = {bias_a, bias_a, bias_a, bias_a};
        c0 = __builtin_amdgcn_mfma_f32_16x16x32_bf16(a0, B1f[0][0], c0, 0, 0, 0);
        c0 = __builtin_amdgcn_mfma_f32_16x16x32_bf16(a1, B1f[1][0], c0, 0, 0, 0);
        f32x4 c1 = {bias_b, bias_b, bias_b, bias_b};
        c1 = __builtin_amdgcn_mfma_f32_16x16x32_bf16(a0, B1f[0][1], c1, 0, 0, 0);
        c1 = __builtin_amdgcn_mfma_f32_16x16x32_bf16(a1, B1f[1][1], c1, 0, 0, 0);
#pragma unroll
        for (int r = 0; r < 4; ++r) {
          h1bf[(q*4 + r)*136 + w*32 + lq]      = f2bf(tanh5(c0[r]));
          h1bf[(q*4 + r)*136 + w*32 + 16 + lq] = f2bf(tanh5(c1[r]));
        }
      }
      lds_barrier();
      // ---- stage 2: h2 = tanh(h1 @ w2 + db2) ----
      {
        short8 h0 = *(const short8*)&h1bf[lq*136 + q*8];
        short8 h1 = *(const short8*)&h1bf[lq*136 + 32 + q*8];
        short8 h2 = *(const short8*)&h1bf[lq*136 + 64 + q*8];
        short8 h3 = *(const short8*)&h1bf[lq*136 + 96 + q*8];
        f32x4 c = {db2v, db2v, db2v, db2v};
        c = __builtin_amdgcn_mfma_f32_16x16x32_bf16(h0, B2f[0], c, 0, 0, 0);
        c = __builtin_amdgcn_mfma_f32_16x16x32_bf16(h1, B2f[1], c, 0, 0, 0);
        c = __builtin_amdgcn_mfma_f32_16x16x32_bf16(h2, B2f[2], c, 0, 0, 0);
        c = __builtin_amdgcn_mfma_f32_16x16x32_bf16(h3, B2f[3], c, 0, 0, 0);
#pragma unroll
        for (int r = 0; r < 4; ++r)
          h2bf[(q*4 + r)*72 + ncol] = f2bf(tanh5(c[r]));
      }
      lds_barrier();
      // ---- stage 3: drift = h2 @ w3 + db3; Euler-Maruyama ----
      {
        short8 g0 = *(const short8*)&h2bf[lq*72 + q*8];
        short8 g1 = *(const short8*)&h2bf[lq*72 + 32 + q*8];
        f32x4 d = {db3v, db3v, db3v, db3v};
        d = __builtin_amdgcn_mfma_f32_16x16x32_bf16(g0, B3f[0], d, 0, 0, 0);
        d = __builtin_amdgcn_mfma_f32_16x16x32_bf16(g1, B3f[1], d, 0, 0, 0);
#pragma unroll
        for (int r = 0; r < 4; ++r) {
          float yv = yreg[r];
          yv = yv + d[r]*hstep + (ca + cb*yv + md)*sqh*dwv[r];
          yreg[r] = yv;
          ybf[(q*4 + r)*72 + ncol] = f2bf(yv);
        }
      }
      // rotate prefetched coefficients
      bias_a = b1na; bias_b = b1nb; ca = can; cb = cbn;
    }
    // write sde_features[:, istep+1]
#pragma unroll
    for (int r = 0; r < 4; ++r) {
      const int gi = ((r0 + q*4 + r)*512 + (istep + 1))*64 + ncol;
      sdebf[gi] = f2bf(yreg[r]);
      outf[160 + gi] = yreg[r];
    }
  }
}

// ---------------- bf16 MFMA GEMM (128x128 tile, 4 waves 2x2) ----------------
// If lng != nullptr (requires N==128, gridDim.y==1): fused epilogue computes
// x = LN(residual + A@B + bias) with residual read from Cf; writes Cf + Cb.
__global__ __launch_bounds__(256) void gemm_bf16_kernel(
    const short* __restrict__ A, const short* __restrict__ BT,
    const float* __restrict__ bias, float* __restrict__ Cf,
    short* __restrict__ Cb, int N, int K, int relu,
    const float* __restrict__ lng, const float* __restrict__ lnb) {
  __shared__ short As[128 * 40];
  __shared__ short Bs[128 * 40];
  __shared__ float rsum[128][2];
  __shared__ float rsq[128][2];
  const int tid = threadIdx.x;
  const int w = tid >> 6, lane = tid & 63, q = lane >> 4, lq = lane & 15;
  const int wm = (w >> 1) * 64, wn = (w & 1) * 64;
  const int bm = blockIdx.x * 128, bn = blockIdx.y * 128;
  const int arow = tid >> 1, ah = (tid & 1) * 16;
  f32x4 acc[4][4];
#pragma unroll
  for (int i = 0; i < 4; ++i)
#pragma unroll
    for (int j = 0; j < 4; ++j) acc[i][j] = (f32x4){0.f, 0.f, 0.f, 0.f};

  for (int k0 = 0; k0 < K; k0 += 32) {
    short8 a0 = *(const short8*)&A[(bm + arow)*K + k0 + ah];
    short8 a1 = *(const short8*)&A[(bm + arow)*K + k0 + ah + 8];
    short8 b0 = *(const short8*)&BT[(bn + arow)*K + k0 + ah];
    short8 b1 = *(const short8*)&BT[(bn + arow)*K + k0 + ah + 8];
    __syncthreads();
    *(short8*)&As[arow*40 + ah]     = a0;
    *(short8*)&As[arow*40 + ah + 8] = a1;
    *(short8*)&Bs[arow*40 + ah]     = b0;
    *(short8*)&Bs[arow*40 + ah + 8] = b1;
    __syncthreads();
    short8 af[4], bf[4];
#pragma unroll
    for (int mi = 0; mi < 4; ++mi)
      af[mi] = *(const short8*)&As[(wm + mi*16 + lq)*40 + q*8];
#pragma unroll
    for (int ni = 0; ni < 4; ++ni)
      bf[ni] = *(const short8*)&Bs[(wn + ni*16 + lq)*40 + q*8];
#pragma unroll
    for (int mi = 0; mi < 4; ++mi)
#pragma unroll
      for (int ni = 0; ni < 4; ++ni)
        acc[mi][ni] = __builtin_amdgcn_mfma_f32_16x16x32_bf16(af[mi], bf[ni],
                                                              acc[mi][ni], 0, 0, 0);
  }
  if (lng == nullptr) {
#pragma unroll
    for (int ni = 0; ni < 4; ++ni) {
      const int col = bn + wn + ni*16 + lq;
      const float bv = bias ? bias[col] : 0.f;
#pragma unroll
      for (int mi = 0; mi < 4; ++mi) {
#pragma unroll
        for (int r = 0; r < 4; ++r) {
          const int row = bm + wm + mi*16 + q*4 + r;
          float v = acc[mi][ni][r] + bv;
          if (relu) v = fmaxf(v, 0.f);
          if (Cf) Cf[row*N + col] = v;
          if (Cb) Cb[row*N + col] = f2bf(v);
        }
      }
    }
  } else {
    // fused residual + LayerNorm epilogue (N == 128)
#pragma unroll
    for (int mi = 0; mi < 4; ++mi) {
#pragma unroll
      for (int r = 0; r < 4; ++r) {
        const int row = bm + wm + mi*16 + q*4 + r;
        float s = 0.f, s2 = 0.f;
#pragma unroll
        for (int ni = 0; ni < 4; ++ni) {
          const int col = wn + ni*16 + lq;
          float v = acc[mi][ni][r] + bias[col] + Cf[row*128 + col];
          acc[mi][ni][r] = v;      // keep for normalize pass
          s += v; s2 += v*v;
        }
#pragma unroll
        for (int off = 1; off < 16; off <<= 1) {
          s  += __shfl_xor(s, off, 16);
          s2 += __shfl_xor(s2, off, 16);
        }
        if (lq == 0) {
          const int lr = wm + mi*16 + q*4 + r;
          rsum[lr][w & 1] = s;
          rsq[lr][w & 1]  = s2;
        }
      }
    }
    __syncthreads();
#pragma unroll
    for (int mi = 0; mi < 4; ++mi) {
#pragma unroll
      for (int r = 0; r < 4; ++r) {
        const int lr = wm + mi*16 + q*4 + r;
        const int row = bm + lr;
        float s = rsum[lr][0] + rsum[lr][1];
        float s2 = rsq[lr][0] + rsq[lr][1];
        float mean = s * (1.f / 128.f);
        float var = s2 * (1.f / 128.f) - mean * mean;
        float inv = rsqrtf(var + 1e-5f);
#pragma unroll
        for (int ni = 0; ni < 4; ++ni) {
          const int col = wn + ni*16 + lq;
          float o = (acc[mi][ni][r] - mean) * inv * lng[col] + lnb[col];
          Cf[row*128 + col] = o;
          Cb[row*128 + col] = f2bf(o);
        }
      }
    }
  }
}

// ---------------- MFMA flash attention, DH=16 (K-dim zero-padded to 32) ----
__global__ __launch_bounds__(256, 1) void attn_kernel(const short* __restrict__ QKV,
                                                      short* __restrict__ O) {
  __shared__ short Kt[512 * 20];    // K [key][d] pitch 20
  __shared__ short Vt[16 * 520];    // V^T [d][key] pitch 520
  __shared__ short Pb[4 * 16 * 520];// per-wave P [qrow][key] pitch 520
  const int blk = blockIdx.x;
  const int qt = blk & 7, h = (blk >> 3) & 7, b = blk >> 6;
  const int tid = threadIdx.x;
  const int w = tid >> 6, lane = tid & 63, q = lane >> 4, lq = lane & 15;

#pragma unroll
  for (int kk = 0; kk < 2; ++kk) {
    const int key = tid + kk*256;
    const short* src = &QKV[(size_t)(b*512 + key)*384 + 128 + h*16];
    short8 k0 = *(const short8*)src;
    short8 k1 = *(const short8*)(src + 8);
    *(short8*)&Kt[key*20]     = k0;
    *(short8*)&Kt[key*20 + 8] = k1;
    short8 v0 = *(const short8*)(src + 128);
    short8 v1 = *(const short8*)(src + 136);
#pragma unroll
    for (int d = 0; d < 8; ++d) Vt[d*520 + key] = v0[d];
#pragma unroll
    for (int d = 0; d < 8; ++d) Vt[(8 + d)*520 + key] = v1[d];
  }
  __syncthreads();

  const int qrow0 = b*512 + qt*64 + w*16;
  short8 aq = (short8){0,0,0,0,0,0,0,0};
  if (q < 2) aq = *(const short8*)&QKV[(size_t)(qrow0 + lq)*384 + h*16 + q*8];

  f32x4 acc[32];
#pragma unroll
  for (int t = 0; t < 32; ++t) {
    short8 bk = (short8){0,0,0,0,0,0,0,0};
    if (q < 2) bk = *(const short8*)&Kt[(t*16 + lq)*20 + q*8];
    f32x4 z = {0.f, 0.f, 0.f, 0.f};
    acc[t] = __builtin_amdgcn_mfma_f32_16x16x32_bf16(aq, bk, z, 0, 0, 0);
  }
  float mx[4] = {-1e30f, -1e30f, -1e30f, -1e30f};
#pragma unroll
  for (int t = 0; t < 32; ++t)
#pragma unroll
    for (int r = 0; r < 4; ++r) mx[r] = fmaxf(mx[r], acc[t][r]);
#pragma unroll
  for (int off = 1; off < 16; off <<= 1)
#pragma unroll
    for (int r = 0; r < 4; ++r) mx[r] = fmaxf(mx[r], __shfl_xor(mx[r], off, 16));
  const float cexp = 0.25f * 1.44269504f;
  float ls[4] = {0.f, 0.f, 0.f, 0.f};
#pragma unroll
  for (int t = 0; t < 32; ++t)
#pragma unroll
    for (int r = 0; r < 4; ++r) {
      float p = __builtin_amdgcn_exp2f((acc[t][r] - mx[r]) * cexp);
      acc[t][r] = p;
      ls[r] += p;
    }
#pragma unroll
  for (int off = 1; off < 16; off <<= 1)
#pragma unroll
    for (int r = 0; r < 4; ++r) ls[r] += __shfl_xor(ls[r], off, 16);
  short* Pw = &Pb[w * 8320];
#pragma unroll
  for (int t = 0; t < 32; ++t)
#pragma unroll
    for (int r = 0; r < 4; ++r)
      Pw[(q*4 + r)*520 + t*16 + lq] = (short)(__float_as_uint(acc[t][r]) >> 16);
  f32x4 o0 = {0.f, 0.f, 0.f, 0.f}, o1 = {0.f, 0.f, 0.f, 0.f};
#pragma unroll
  for (int kt = 0; kt < 16; kt += 2) {
    short8 ap0 = *(const short8*)&Pw[lq*520 + kt*32 + q*8];
    short8 bv0 = *(const short8*)&Vt[lq*520 + kt*32 + q*8];
    short8 ap1 = *(const short8*)&Pw[lq*520 + (kt + 1)*32 + q*8];
    short8 bv1 = *(const short8*)&Vt[lq*520 + (kt + 1)*32 + q*8];
    o0 = __builtin_amdgcn_mfma_f32_16x16x32_bf16(ap0, bv0, o0, 0, 0, 0);
    o1 = __builtin_amdgcn_mfma_f32_16x16x32_bf16(ap1, bv1, o1, 0, 0, 0);
  }
#pragma unroll
  for (int r = 0; r < 4; ++r) {
    float ov = (o0[r] + o1[r]) * __builtin_amdgcn_rcpf(ls[r]);
    O[(size_t)(qrow0 + q*4 + r)*128 + h*16 + lq] = f2bf(ov);
  }
}

// ---------------- mean-pool + 2-layer classifier ----------------
__global__ __launch_bounds__(128) void pool_cls_kernel(const float* __restrict__ W,
                                                       float* __restrict__ outf) {
  int b = blockIdx.x, j = threadIdx.x;
  float s = 0.f;
  for (int ss = 0; ss < 512; ++ss) s += W[OFF_X + ((b*512 + ss)*128) + j];
  __shared__ float pooled[128];
  __shared__ float hid[64];
  pooled[j] = s * (1.f / 512.f);
  __syncthreads();
  if (j < 64) {
    float a = W[OFF_CB1 + j];
    for (int i = 0; i < 128; ++i) a += pooled[i] * W[OFF_CW1 + i*64 + j];
    hid[j] = fmaxf(a, 0.f);
  }
  __syncthreads();
  if (j < 5) {
    float a = W[OFF_CB2 + j];
    for (int i = 0; i < 64; ++i) a += hid[i] * W[OFF_CW2 + i*5 + j];
    outf[b*5 + j] = a;
  }
}

// ---------------- launch ----------------
extern "C" void kernel_launch(void* const* d_in, const int* in_sizes, int n_in,
                              void* d_out, int out_size, void* d_ws, size_t ws_size,
                              hipStream_t stream) {
  (void)in_sizes; (void)out_size; (void)ws_size;
  float* W = reinterpret_cast<float*>(d_ws);
  float* outf = reinterpret_cast<float*>(d_out);
  short* sdebf = (short*)(W + OFF_SDEBF);
  short* xbf   = (short*)(W + OFF_XBF);
  short* qkvbf = (short*)(W + OFF_QKVBF);
  short* obf   = (short*)(W + OFF_OBF);
  short* hbf   = (short*)(W + OFF_HBF);
  PtrPack pk;
  for (int i = 0; i < 45 && i < n_in; ++i) pk.p[i] = d_in[i];

  ingest_kernel<<<512, 256, 0, stream>>>(pk, W);
  prep_kernel<<<512, 256, 0, stream>>>(W);
  encoder_kernel<<<16384, 64, 0, stream>>>(W, outf);
  precompute_kernel<<<5110, 128, 0, stream>>>(W);
  sde_kernel<<<22, 256, 0, stream>>>(W, d_in[2], outf);

  // x = sde_features @ in_w + in_b  (fp32 master + bf16 mirror)
  gemm_bf16_kernel<<<dim3(128, 1), 256, 0, stream>>>(sdebf, (short*)(W + OFF_INWT),
      W + OFF_INB, W + OFF_X, xbf, 128, 64, 0, nullptr, nullptr);
  for (int l = 0; l < 4; ++l) {
    gemm_bf16_kernel<<<dim3(128, 3), 256, 0, stream>>>(xbf,
        (short*)(W + OFF_WQKVT) + l*49152, W + OFF_BQKV + l*384,
        (float*)nullptr, qkvbf, 384, 128, 0, nullptr, nullptr);
    attn_kernel<<<2048, 256, 0, stream>>>(qkvbf, obf);
    // wo-gemm with fused residual+LN1 (reads/writes X, writes xbf)
    gemm_bf16_kernel<<<dim3(128, 1), 256, 0, stream>>>(obf,
        (short*)(W + OFF_WOT) + l*16384, W + OFF_BO + l*128,
        W + OFF_X, xbf, 128, 128, 0, W + OFF_LN1G + l*128, W + OFF_LN1B + l*128);
    gemm_bf16_kernel<<<dim3(128, 4), 256, 0, stream>>>(xbf,
        (short*)(W + OFF_FW1T) + l*65536, W + OFF_FB1 + l*512,
        (float*)nullptr, hbf, 512, 128, 1, nullptr, nullptr);
    // fw2-gemm with fused residual+LN2
    gemm_bf16_kernel<<<dim3(128, 1), 256, 0, stream>>>(hbf,
        (short*)(W + OFF_FW2T) + l*65536, W + OFF_FB2 + l*128,
        W + OFF_X, xbf, 128, 512, 0, W + OFF_LN2G + l*128, W + OFF_LN2B + l*128);
  }
  pool_cls_kernel<<<32, 128, 0, stream>>>(W, outf);
}

// Round 8
// 1025.579 us; speedup vs baseline: 1.9570x; 1.1411x over previous
//
#include <hip/hip_runtime.h>
#include <hip/hip_bf16.h>

// ============================================================
// B=32, S=512, IN=3, H=64, D=128, NH=8, DH=16, L=4, C=5
// NSUB=10, MAX_CONSEC=50 -> SDE splits into 11 independent
// segments (state resets to enc at s % 51 == 0).
// Outputs (fp32): logits (160) then sde_features (32*512*64).
// R8: attn -> one block per (b,h), K/V staged once, chunked P;
// M64 GEMM w/ intra-wave LN for N=128 gemms; sde stage2 chain
// split; unrolled pooling.
// ============================================================

typedef __attribute__((ext_vector_type(8))) short short8;
typedef __attribute__((ext_vector_type(4))) float f32x4;

// ---------------- ws layout (float element offsets) ----------------
static constexpr int OFF_TS      = 0;         // 49152
static constexpr int OFF_TIMES   = 49152;     // 16384
static constexpr int OFF_ENCW    = 65536;     // 192
static constexpr int OFF_ENCB    = 65728;     // 64
static constexpr int OFF_ENCG    = 65792;     // 64
static constexpr int OFF_ENCBETA = 65856;     // 64
static constexpr int OFF_DW1     = 65920;     // 8320 (65x128)
static constexpr int OFF_DB1     = 74240;     // 128
static constexpr int OFF_DW2     = 74368;     // 8192 (128x64)
static constexpr int OFF_DB2     = 82560;     // 64
static constexpr int OFF_DW3     = 82624;     // 4096 (64x64)
static constexpr int OFF_DB3     = 86720;     // 64
static constexpr int OFF_AW1     = 86784;     // 64
static constexpr int OFF_AB1     = 86848;     // 64
static constexpr int OFF_AW2     = 86912;     // 4096
static constexpr int OFF_AB2     = 91008;     // 64
static constexpr int OFF_BW1     = 91072;     // 64
static constexpr int OFF_BB1     = 91136;     // 64
static constexpr int OFF_BW2     = 91200;     // 4096
static constexpr int OFF_BB2     = 95296;     // 64
static constexpr int OFF_MD      = 95360;     // 1
static constexpr int OFF_INW     = 95424;     // 8192 (64x128)
static constexpr int OFF_INB     = 103616;    // 128
static constexpr int OFF_WQ      = 103744;    // 4*128*128
static constexpr int OFF_BQ      = 169280;    // 4*128
static constexpr int OFF_WK      = 169792;
static constexpr int OFF_BK      = 235328;
static constexpr int OFF_WV      = 235840;
static constexpr int OFF_BV      = 301376;
static constexpr int OFF_WO      = 301888;
static constexpr int OFF_BO      = 367424;
static constexpr int OFF_LN1G    = 367936;    // 4*128
static constexpr int OFF_LN1B    = 368448;
static constexpr int OFF_LN2G    = 368960;
static constexpr int OFF_LN2B    = 369472;
static constexpr int OFF_FW1     = 369984;    // 4*128*512
static constexpr int OFF_FB1     = 632128;    // 4*512
static constexpr int OFF_FW2     = 634176;    // 4*512*128
static constexpr int OFF_FB2     = 896320;    // 4*128
static constexpr int OFF_CW1     = 896832;    // 128*64
static constexpr int OFF_CB1     = 905024;    // 64
static constexpr int OFF_CW2     = 905088;    // 64*5 (pad)
static constexpr int OFF_CB2     = 905472;    // 5 (pad)
static constexpr int OFF_FLAG    = 905536;    // int flag: 1 = noise is bf16
// compute buffers
static constexpr int OFF_ENC     = 905600;    // 32*512*64 fp32
static constexpr int OFF_COEFA   = 3002752;   // 5110*64
static constexpr int OFF_COEFB   = 3329792;   // 5110*64
static constexpr int OFF_B1C     = 3656832;   // 5110*128
static constexpr int OFF_X       = 4310912;   // 16384*128 fp32 (residual master)
// bf16 buffers
static constexpr int OFF_XBF     = 6408064;   // 16384*128 bf16 (1048576 f)
static constexpr int OFF_QKVBF   = 7456640;   // 16384*384 bf16 (3145728 f)
static constexpr int OFF_OBF     = 10602368;  // 16384*128 bf16
static constexpr int OFF_HBF     = 11650944;  // 16384*512 bf16 (4194304 f)
static constexpr int OFF_SDEBF   = 15845248;  // 16384*64 bf16 (524288 f)
static constexpr int OFF_WQKVT   = 16369536;  // 4*384*128 bf16 (98304 f)
static constexpr int OFF_WOT     = 16467840;  // 4*128*128 bf16 (32768 f)
static constexpr int OFF_FW1T    = 16500608;  // 4*512*128 bf16 (131072 f)
static constexpr int OFF_FW2T    = 16631680;  // 4*128*512 bf16 (131072 f)
static constexpr int OFF_INWT    = 16762752;  // 128*64 bf16 (4096 f)
static constexpr int OFF_BQKV    = 16766848;  // 4*384 fp32
static constexpr int OFF_TMP     = 23185280;  // 16384*128 fp32 (unused now)
// total = 25282432 floats ~= 96.5 MiB

struct PtrPack { const void* p[45]; };

// ---------------- helpers ----------------
__device__ inline float wsum64(float v) {
#pragma unroll
  for (int off = 32; off > 0; off >>= 1) v += __shfl_xor(v, off, 64);
  return v;
}

__device__ inline float fast_tanh(float x) {
  x = fminf(fmaxf(x, -15.f), 15.f);
  float e = __expf(2.f * x);
  return (e - 1.f) / (e + 1.f);
}

// 5-instr tanh: 1 - 2/(exp2(2x*log2e)+1); saturates correctly at +-inf
__device__ inline float tanh5(float x) {
  float e = __builtin_amdgcn_exp2f(x * 2.88539008f);
  return 1.f - 2.f * __builtin_amdgcn_rcpf(e + 1.f);
}

__device__ inline float bfdec(unsigned short h) {
  return __uint_as_float(((unsigned)h) << 16);
}

// round-to-nearest-even f32 -> bf16 bits
__device__ inline short f2bf(float f) {
  unsigned u = __float_as_uint(f);
  return (short)((u + 0x7FFFu + ((u >> 16) & 1u)) >> 16);
}

// workgroup barrier that drains ONLY LDS ops (no vmcnt drain -> global
// prefetches stay in flight across it)
__device__ inline void lds_barrier() {
  asm volatile("s_waitcnt lgkmcnt(0)\ns_barrier" ::: "memory");
}

// ---------------- ingest: convert all float inputs to f32 mirrors ----------------
__global__ __launch_bounds__(256) void ingest_kernel(PtrPack pk, float* __restrict__ W) {
  const int NE = 43;
  const int cnt[NE] = {49152,16384,192,64,64,64,8320,128,8192,64,4096,64,64,64,4096,64,
                       64,64,4096,64,1,8192,128,65536,512,65536,512,65536,512,65536,512,
                       512,512,512,512,262144,2048,262144,512,8192,64,320,5};
  const int src[NE] = {0,1,4,5,6,7,8,9,10,11,12,13,14,15,16,17,18,19,20,21,22,23,24,
                       25,26,27,28,29,30,31,32,33,34,35,36,37,38,39,40,41,42,43,44};
  const int dst[NE] = {OFF_TS,OFF_TIMES,OFF_ENCW,OFF_ENCB,OFF_ENCG,OFF_ENCBETA,OFF_DW1,
                       OFF_DB1,OFF_DW2,OFF_DB2,OFF_DW3,OFF_DB3,OFF_AW1,OFF_AB1,OFF_AW2,
                       OFF_AB2,OFF_BW1,OFF_BB1,OFF_BW2,OFF_BB2,OFF_MD,OFF_INW,OFF_INB,
                       OFF_WQ,OFF_BQ,OFF_WK,OFF_BK,OFF_WV,OFF_BV,OFF_WO,OFF_BO,
                       OFF_LN1G,OFF_LN1B,OFF_LN2G,OFF_LN2B,OFF_FW1,OFF_FB1,OFF_FW2,
                       OFF_FB2,OFF_CW1,OFF_CB1,OFF_CW2,OFF_CB2};
  const unsigned* eg = (const unsigned*)pk.p[6];     // enc_g (all ones)
  int gmode = (eg[0] == 0x3F803F80u) ? 1 : 0;

  __shared__ int isbf[NE];
  if (threadIdx.x < NE) {
    int k = threadIdx.x;
    int f = gmode;
    if (gmode) {
      const unsigned short* us = (const unsigned short*)pk.p[src[k]];
      int n = cnt[k] < 32 ? cnt[k] : 32;
      for (int i = 0; i < n; ++i) {
        unsigned short h = us[i];
        if (h & 0x7FFF) {
          float a = fabsf(bfdec(h));
          if (!(a > 1e-20f && a < 1e4f)) { f = 0; break; }
        }
      }
    }
    isbf[k] = f;
  }
  __syncthreads();

  int gid = blockIdx.x * 256 + threadIdx.x;
  int stride = gridDim.x * 256;
  if (gid == 0) {
    int nf = gmode;
    if (gmode) {
      const unsigned short* us = (const unsigned short*)pk.p[2];
      for (int i = 0; i < 32; ++i) {
        unsigned short h = us[i];
        if (h & 0x7FFF) {
          float a = fabsf(bfdec(h));
          if (!(a > 1e-20f && a < 1e4f)) { nf = 0; break; }
        }
      }
    }
    ((int*)W)[OFF_FLAG] = nf;
  }
  for (int k = 0; k < NE; ++k) {
    int n = cnt[k];
    float* dp = W + dst[k];
    if (isbf[k]) {
      const unsigned short* us = (const unsigned short*)pk.p[src[k]];
      for (int e = gid; e < n; e += stride) dp[e] = bfdec(us[e]);
    } else {
      const float* fs = (const float*)pk.p[src[k]];
      for (int e = gid; e < n; e += stride) dp[e] = fs[e];
    }
  }
}

// ---------------- prep: transpose transformer weights to bf16 N-major ----------------
__global__ __launch_bounds__(256) void prep_kernel(float* __restrict__ W) {
  short* wqkvT = (short*)(W + OFF_WQKVT);
  short* woT   = (short*)(W + OFF_WOT);
  short* fw1T  = (short*)(W + OFF_FW1T);
  short* fw2T  = (short*)(W + OFF_FW2T);
  short* inwT  = (short*)(W + OFF_INWT);
  float* bqkv  = W + OFF_BQKV;
  int gid = blockIdx.x * 256 + threadIdx.x;
  int stride = gridDim.x * 256;
  for (int e = gid; e < 796160; e += stride) {
    if (e < 196608) {            // wqkvT[l][384][128]
      int l = e / 49152, r = e % 49152, n = r >> 7, k = r & 127;
      float v = (n < 128) ? W[OFF_WQ + l*16384 + k*128 + n]
              : (n < 256) ? W[OFF_WK + l*16384 + k*128 + (n - 128)]
                          : W[OFF_WV + l*16384 + k*128 + (n - 256)];
      wqkvT[e] = f2bf(v);
    } else if (e < 262144) {     // woT[l][128][128]
      int t = e - 196608; int l = t / 16384, r = t % 16384, n = r >> 7, k = r & 127;
      woT[t] = f2bf(W[OFF_WO + l*16384 + k*128 + n]);
    } else if (e < 524288) {     // fw1T[l][512][128]
      int t = e - 262144; int l = t / 65536, r = t % 65536, n = r >> 7, k = r & 127;
      fw1T[t] = f2bf(W[OFF_FW1 + l*65536 + k*512 + n]);
    } else if (e < 786432) {     // fw2T[l][128][512]
      int t = e - 524288; int l = t / 65536, r = t % 65536, n = r >> 9, k = r & 511;
      fw2T[t] = f2bf(W[OFF_FW2 + l*65536 + k*128 + n]);
    } else if (e < 794624) {     // inwT[128][64]
      int t = e - 786432; int n = t >> 6, k = t & 63;
      inwT[t] = f2bf(W[OFF_INW + k*128 + n]);
    } else {                     // bqkv[4][384] fp32
      int t = e - 794624; int l = t / 384, j = t % 384;
      bqkv[t] = (j < 128) ? W[OFF_BQ + l*128 + j]
              : (j < 256) ? W[OFF_BK + l*128 + (j - 128)]
                          : W[OFF_BV + l*128 + (j - 256)];
    }
  }
}

// ---------------- encoder: enc = relu(LN(ts @ enc_w + enc_b)) ----------------
__global__ __launch_bounds__(64) void encoder_kernel(float* __restrict__ W,
                                                     float* __restrict__ outf) {
  int row = blockIdx.x;        // b*512 + s
  int j = threadIdx.x;
  float t0 = W[OFF_TS + row*3 + 0];
  float t1 = W[OFF_TS + row*3 + 1];
  float t2 = W[OFF_TS + row*3 + 2];
  float v = W[OFF_ENCB + j] + t0 * W[OFF_ENCW + j] + t1 * W[OFF_ENCW + 64 + j]
          + t2 * W[OFF_ENCW + 128 + j];
  float mean = wsum64(v) * (1.f / 64.f);
  float d = v - mean;
  float var = wsum64(d * d) * (1.f / 64.f);
  float o = d * rsqrtf(var + 1e-5f) * W[OFF_ENCG + j] + W[OFF_ENCBETA + j];
  o = fmaxf(o, 0.f);
  W[OFF_ENC + row*64 + j] = o;
  int s = row & 511;
  if (s % 51 == 0) {           // reset positions: sde_features[:,s] = enc[:,s]
    ((short*)(W + OFF_SDEBF))[row*64 + j] = f2bf(o);
    outf[160 + row*64 + j] = o;
  }
}

// ---------------- precompute A(t), Bt(t), bias1(t) ----------------
__global__ __launch_bounds__(128) void precompute_kernel(float* __restrict__ W) {
  int bi = blockIdx.x;             // 0..5109
  int step = bi / 10, k = bi - step * 10;
  float t_prev = W[OFF_TIMES + step];
  float t_cur  = W[OFF_TIMES + step + 1];
  float h = (t_cur - t_prev) * 0.1f;
  float t = t_prev + (float)k * h;
  __shared__ float av[64], bv[64];
  int tid = threadIdx.x;
  if (tid < 64) av[tid] = fast_tanh(t * W[OFF_AW1 + tid] + W[OFF_AB1 + tid]);
  else { int j = tid - 64; bv[j] = fast_tanh(t * W[OFF_BW1 + j] + W[OFF_BB1 + j]); }
  __syncthreads();
  if (tid < 64) {
    float a = W[OFF_AB2 + tid];
    for (int i = 0; i < 64; ++i) a += av[i] * W[OFF_AW2 + i*64 + tid];
    W[OFF_COEFA + bi*64 + tid] = fmaxf(a, 0.f) + log1pf(__expf(-fabsf(a)));
  } else {
    int j = tid - 64;
    float a = W[OFF_BB2 + j];
    for (int i = 0; i < 64; ++i) a += bv[i] * W[OFF_BW2 + i*64 + j];
    W[OFF_COEFB + bi*64 + j] = fast_tanh(a);
  }
  W[OFF_B1C + bi*128 + tid] = t * W[OFF_DW1 + 64*128 + tid] + W[OFF_DB1 + tid];
}

// ---------------- SDE integrator: 22 blocks, 4 waves split N ----------------
__global__ __launch_bounds__(256, 1) void sde_kernel(float* __restrict__ W,
                                                     const void* __restrict__ noise,
                                                     float* __restrict__ outf) {
  __shared__ short ybf[16 * 72];     // y bf16 [m][k] pitch 72
  __shared__ short h1bf[16 * 136];   // h1 [m][k] pitch 136
  __shared__ short h2bf[16 * 72];    // h2 [m][k] pitch 72

  const int tid = threadIdx.x;
  const int w   = tid >> 6;
  const int lane = tid & 63;
  const int q   = lane >> 4;
  const int lq  = lane & 15;
  const int g   = blockIdx.x >> 1;          // segment 0..10
  const int r0  = (blockIdx.x & 1) * 16;    // batch rows r0..r0+15

  const int nmode = ((const int*)W)[OFF_FLAG];
  const float md = fabsf(W[OFF_MD]);
  const unsigned short* nb16 = (const unsigned short*)noise;
  const float* nf32 = (const float*)noise;
  short* sdebf = (short*)(W + OFF_SDEBF);

  const int ncol = w*16 + lq;
  short8 B1f[2][2];
#pragma unroll
  for (int kt = 0; kt < 2; ++kt)
#pragma unroll
    for (int ct = 0; ct < 2; ++ct)
#pragma unroll
      for (int j = 0; j < 8; ++j)
        B1f[kt][ct][j] = f2bf(W[OFF_DW1 + (kt*32 + q*8 + j)*128 + w*32 + ct*16 + lq]);
  short8 B2f[4];
#pragma unroll
  for (int kt = 0; kt < 4; ++kt)
#pragma unroll
    for (int j = 0; j < 8; ++j)
      B2f[kt][j] = f2bf(W[OFF_DW2 + (kt*32 + q*8 + j)*64 + ncol]);
  short8 B3f[2];
#pragma unroll
  for (int kt = 0; kt < 2; ++kt)
#pragma unroll
    for (int j = 0; j < 8; ++j)
      B3f[kt][j] = f2bf(W[OFF_DW3 + (kt*32 + q*8 + j)*64 + ncol]);
  const float db2v = W[OFF_DB2 + ncol];
  const float db3v = W[OFF_DB3 + ncol];

  float yreg[4];
#pragma unroll
  for (int r = 0; r < 4; ++r) {
    yreg[r] = W[OFF_ENC + ((r0 + q*4 + r)*512 + 51*g)*64 + ncol];
    ybf[(q*4 + r)*72 + ncol] = f2bf(yreg[r]);
  }

  const int ci0 = 51*g*10;
  float bias_a = W[OFF_B1C + ci0*128 + w*32 + lq];
  float bias_b = W[OFF_B1C + ci0*128 + w*32 + 16 + lq];
  float ca = W[OFF_COEFA + ci0*64 + ncol];
  float cb = W[OFF_COEFB + ci0*64 + ncol];

  const int nsteps = (g == 10) ? 1 : 50;
  for (int m = 0; m < nsteps; ++m) {
    const int istep = 51*g + m;
    const float t_prev = W[OFF_TIMES + istep];
    const float t_cur  = W[OFF_TIMES + istep + 1];
    const float hstep = (t_cur - t_prev) * 0.1f;
    const float sqh = sqrtf(hstep);
    for (int k = 0; k < 10; ++k) {
      const int ci = istep*10 + k;
      const int cin = (ci + 1 > 5109) ? 5109 : ci + 1;
      float b1na = W[OFF_B1C + cin*128 + w*32 + lq];
      float b1nb = W[OFF_B1C + cin*128 + w*32 + 16 + lq];
      float can = W[OFF_COEFA + cin*64 + ncol];
      float cbn = W[OFF_COEFB + cin*64 + ncol];
      float dwv[4];
      {
        const int nb = (((istep + 1)*10 + k)*32 + r0 + q*4)*64 + ncol;
#pragma unroll
        for (int r = 0; r < 4; ++r)
          dwv[r] = nmode ? bfdec(nb16[nb + r*64]) : nf32[nb + r*64];
      }
      lds_barrier();   // ybf (prev stage3 / init) visible
      // ---- stage 1 ----
      {
        short8 a0 = *(const short8*)&ybf[lq*72 + q*8];
        short8 a1 = *(const short8*)&ybf[lq*72 + 32 + q*8];
        f32x4 c0 = {bias_a, bias_a, bias_a, bias_a};
        c0 = __builtin_amdgcn_mfma_f32_16x16x32_bf16(a0, B1f[0][0], c0, 0, 0, 0);
        c0 = __builtin_amdgcn_mfma_f32_16x16x32_bf16(a1, B1f[1][0], c0, 0, 0, 0);
        f32x4 c1 = {bias_b, bias_b, bias_b, bias_b};
        c1 = __builtin_amdgcn_mfma_f32_16x16x32_bf16(a0, B1f[0][1], c1, 0, 0, 0);
        c1 = __builtin_amdgcn_mfma_f32_16x16x32_bf16(a1, B1f[1][1], c1, 0, 0, 0);
#pragma unroll
        for (int r = 0; r < 4; ++r) {
          h1bf[(q*4 + r)*136 + w*32 + lq]      = f2bf(tanh5(c0[r]));
          h1bf[(q*4 + r)*136 + w*32 + 16 + lq] = f2bf(tanh5(c1[r]));
        }
      }
      lds_barrier();
      // ---- stage 2 (split 2+2 accumulators to halve MFMA dep chain) ----
      {
        short8 h0 = *(const short8*)&h1bf[lq*136 + q*8];
        short8 h1 = *(const short8*)&h1bf[lq*136 + 32 + q*8];
        short8 h2 = *(const short8*)&h1bf[lq*136 + 64 + q*8];
        short8 h3 = *(const short8*)&h1bf[lq*136 + 96 + q*8];
        f32x4 cA = {db2v, db2v, db2v, db2v};
        cA = __builtin_amdgcn_mfma_f32_16x16x32_bf16(h0, B2f[0], cA, 0, 0, 0);
        cA = __builtin_amdgcn_mfma_f32_16x16x32_bf16(h1, B2f[1], cA, 0, 0, 0);
        f32x4 cB = {0.f, 0.f, 0.f, 0.f};
        cB = __builtin_amdgcn_mfma_f32_16x16x32_bf16(h2, B2f[2], cB, 0, 0, 0);
        cB = __builtin_amdgcn_mfma_f32_16x16x32_bf16(h3, B2f[3], cB, 0, 0, 0);
#pragma unroll
        for (int r = 0; r < 4; ++r)
          h2bf[(q*4 + r)*72 + ncol] = f2bf(tanh5(cA[r] + cB[r]));
      }
      lds_barrier();
      // ---- stage 3 ----
      {
        short8 g0 = *(const short8*)&h2bf[lq*72 + q*8];
        short8 g1 = *(const short8*)&h2bf[lq*72 + 32 + q*8];
        f32x4 d = {db3v, db3v, db3v, db3v};
        d = __builtin_amdgcn_mfma_f32_16x16x32_bf16(g0, B3f[0], d, 0, 0, 0);
        d = __builtin_amdgcn_mfma_f32_16x16x32_bf16(g1, B3f[1], d, 0, 0, 0);
#pragma unroll
        for (int r = 0; r < 4; ++r) {
          float yv = yreg[r];
          yv = yv + d[r]*hstep + (ca + cb*yv + md)*sqh*dwv[r];
          yreg[r] = yv;
          ybf[(q*4 + r)*72 + ncol] = f2bf(yv);
        }
      }
      bias_a = b1na; bias_b = b1nb; ca = can; cb = cbn;
    }
#pragma unroll
    for (int r = 0; r < 4; ++r) {
      const int gi = ((r0 + q*4 + r)*512 + (istep + 1))*64 + ncol;
      sdebf[gi] = f2bf(yreg[r]);
      outf[160 + gi] = yreg[r];
    }
  }
}

// ---------------- bf16 MFMA GEMM (128x128 tile, 4 waves 2x2) ----------------
__global__ __launch_bounds__(256) void gemm_bf16_kernel(
    const short* __restrict__ A, const short* __restrict__ BT,
    const float* __restrict__ bias, float* __restrict__ Cf,
    short* __restrict__ Cb, int N, int K, int relu) {
  __shared__ short As[128 * 40];
  __shared__ short Bs[128 * 40];
  const int tid = threadIdx.x;
  const int w = tid >> 6, lane = tid & 63, q = lane >> 4, lq = lane & 15;
  const int wm = (w >> 1) * 64, wn = (w & 1) * 64;
  const int bm = blockIdx.x * 128, bn = blockIdx.y * 128;
  const int arow = tid >> 1, ah = (tid & 1) * 16;
  f32x4 acc[4][4];
#pragma unroll
  for (int i = 0; i < 4; ++i)
#pragma unroll
    for (int j = 0; j < 4; ++j) acc[i][j] = (f32x4){0.f, 0.f, 0.f, 0.f};

  for (int k0 = 0; k0 < K; k0 += 32) {
    short8 a0 = *(const short8*)&A[(bm + arow)*K + k0 + ah];
    short8 a1 = *(const short8*)&A[(bm + arow)*K + k0 + ah + 8];
    short8 b0 = *(const short8*)&BT[(bn + arow)*K + k0 + ah];
    short8 b1 = *(const short8*)&BT[(bn + arow)*K + k0 + ah + 8];
    __syncthreads();
    *(short8*)&As[arow*40 + ah]     = a0;
    *(short8*)&As[arow*40 + ah + 8] = a1;
    *(short8*)&Bs[arow*40 + ah]     = b0;
    *(short8*)&Bs[arow*40 + ah + 8] = b1;
    __syncthreads();
    short8 af[4], bf[4];
#pragma unroll
    for (int mi = 0; mi < 4; ++mi)
      af[mi] = *(const short8*)&As[(wm + mi*16 + lq)*40 + q*8];
#pragma unroll
    for (int ni = 0; ni < 4; ++ni)
      bf[ni] = *(const short8*)&Bs[(wn + ni*16 + lq)*40 + q*8];
#pragma unroll
    for (int mi = 0; mi < 4; ++mi)
#pragma unroll
      for (int ni = 0; ni < 4; ++ni)
        acc[mi][ni] = __builtin_amdgcn_mfma_f32_16x16x32_bf16(af[mi], bf[ni],
                                                              acc[mi][ni], 0, 0, 0);
  }
#pragma unroll
  for (int ni = 0; ni < 4; ++ni) {
    const int col = bn + wn + ni*16 + lq;
    const float bv = bias ? bias[col] : 0.f;
#pragma unroll
    for (int mi = 0; mi < 4; ++mi) {
#pragma unroll
      for (int r = 0; r < 4; ++r) {
        const int row = bm + wm + mi*16 + q*4 + r;
        float v = acc[mi][ni][r] + bv;
        if (relu) v = fmaxf(v, 0.f);
        if (Cf) Cf[row*N + col] = v;
        if (Cb) Cb[row*N + col] = f2bf(v);
      }
    }
  }
}

// ---------------- M64 GEMM, N=128, optional fused residual+LN ----------------
// 256 blocks of 64 rows; wave w owns rows [w*16, w*16+16) x all 128 cols ->
// LN reduce is pure 16-lane shuffles (no cross-wave traffic).
__global__ __launch_bounds__(256) void gemm_ln64_kernel(
    const short* __restrict__ A, const short* __restrict__ BT,
    const float* __restrict__ bias, float* __restrict__ X,
    short* __restrict__ Xb, int K,
    const float* __restrict__ lng, const float* __restrict__ lnb) {
  __shared__ short As[64 * 40];
  __shared__ short Bs[128 * 40];
  const int tid = threadIdx.x;
  const int w = tid >> 6, lane = tid & 63, q = lane >> 4, lq = lane & 15;
  const int bm = blockIdx.x * 64;
  f32x4 acc[8];
#pragma unroll
  for (int i = 0; i < 8; ++i) acc[i] = (f32x4){0.f, 0.f, 0.f, 0.f};

  const int arow = tid >> 2, acol = (tid & 3) * 8;
  const int brow = tid >> 1, bcol = (tid & 1) * 16;
  for (int k0 = 0; k0 < K; k0 += 32) {
    short8 a  = *(const short8*)&A[(bm + arow)*K + k0 + acol];
    short8 b0 = *(const short8*)&BT[brow*K + k0 + bcol];
    short8 b1 = *(const short8*)&BT[brow*K + k0 + bcol + 8];
    __syncthreads();
    *(short8*)&As[arow*40 + acol]    = a;
    *(short8*)&Bs[brow*40 + bcol]    = b0;
    *(short8*)&Bs[brow*40 + bcol+8]  = b1;
    __syncthreads();
    short8 af = *(const short8*)&As[(w*16 + lq)*40 + q*8];
#pragma unroll
    for (int ni = 0; ni < 8; ++ni) {
      short8 bf = *(const short8*)&Bs[(ni*16 + lq)*40 + q*8];
      acc[ni] = __builtin_amdgcn_mfma_f32_16x16x32_bf16(af, bf, acc[ni], 0, 0, 0);
    }
  }
  if (lng == nullptr) {
#pragma unroll
    for (int r = 0; r < 4; ++r) {
      const int row = bm + w*16 + q*4 + r;
#pragma unroll
      for (int ni = 0; ni < 8; ++ni) {
        const int col = ni*16 + lq;
        float v = acc[ni][r] + bias[col];
        X[row*128 + col] = v;
        Xb[row*128 + col] = f2bf(v);
      }
    }
  } else {
#pragma unroll
    for (int r = 0; r < 4; ++r) {
      const int row = bm + w*16 + q*4 + r;
      float v[8];
      float s = 0.f, s2 = 0.f;
#pragma unroll
      for (int ni = 0; ni < 8; ++ni) {
        const int col = ni*16 + lq;
        float t = acc[ni][r] + bias[col] + X[row*128 + col];
        v[ni] = t; s += t; s2 += t*t;
      }
#pragma unroll
      for (int off = 1; off < 16; off <<= 1) {
        s  += __shfl_xor(s, off, 16);
        s2 += __shfl_xor(s2, off, 16);
      }
      float mean = s * (1.f / 128.f);
      float var = s2 * (1.f / 128.f) - mean * mean;
      float inv = rsqrtf(var + 1e-5f);
#pragma unroll
      for (int ni = 0; ni < 8; ++ni) {
        const int col = ni*16 + lq;
        float o = (v[ni] - mean) * inv * lng[col] + lnb[col];
        X[row*128 + col] = o;
        Xb[row*128 + col] = f2bf(o);
      }
    }
  }
}

// ---------------- MFMA flash attention: one block per (b,h) ----------------
// K/V staged ONCE; 4 waves x 8 q-tiles of 16 rows; P chunked through a
// per-wave LDS buffer (intra-wave in-order LDS -> no barriers in loop).
__global__ __launch_bounds__(256) void attn_kernel(const short* __restrict__ QKV,
                                                   short* __restrict__ O) {
  __shared__ short Kt[512 * 20];    // K [key][d] pitch 20
  __shared__ short Vt[16 * 520];    // V^T [d][key] pitch 520
  __shared__ short Pb[4 * 16 * 136];// per-wave P chunk [qrow][key128] pitch 136
  const int blk = blockIdx.x;       // 256 blocks
  const int h = blk & 7, b = blk >> 3;
  const int tid = threadIdx.x;
  const int w = tid >> 6, lane = tid & 63, q = lane >> 4, lq = lane & 15;

#pragma unroll
  for (int kk = 0; kk < 2; ++kk) {
    const int key = tid + kk*256;
    const short* src = &QKV[(size_t)(b*512 + key)*384 + 128 + h*16];
    short8 k0 = *(const short8*)src;
    short8 k1 = *(const short8*)(src + 8);
    *(short8*)&Kt[key*20]     = k0;
    *(short8*)&Kt[key*20 + 8] = k1;
    short8 v0 = *(const short8*)(src + 128);
    short8 v1 = *(const short8*)(src + 136);
#pragma unroll
    for (int d = 0; d < 8; ++d) Vt[d*520 + key] = v0[d];
#pragma unroll
    for (int d = 0; d < 8; ++d) Vt[(8 + d)*520 + key] = v1[d];
  }
  __syncthreads();

  short* Pw = &Pb[w * 2176];
  const float cexp = 0.25f * 1.44269504f;   // scale/sqrt(DH) folded into exp2

  for (int qi = 0; qi < 8; ++qi) {
    const int qrow0 = b*512 + (w*8 + qi)*16;
    short8 aq = (short8){0,0,0,0,0,0,0,0};
    if (q < 2) aq = *(const short8*)&QKV[(size_t)(qrow0 + lq)*384 + h*16 + q*8];

    f32x4 acc[32];
#pragma unroll
    for (int t = 0; t < 32; ++t) {
      short8 bk = (short8){0,0,0,0,0,0,0,0};
      if (q < 2) bk = *(const short8*)&Kt[(t*16 + lq)*20 + q*8];
      f32x4 z = {0.f, 0.f, 0.f, 0.f};
      acc[t] = __builtin_amdgcn_mfma_f32_16x16x32_bf16(aq, bk, z, 0, 0, 0);
    }
    float mx[4] = {-1e30f, -1e30f, -1e30f, -1e30f};
#pragma unroll
    for (int t = 0; t < 32; ++t)
#pragma unroll
      for (int r = 0; r < 4; ++r) mx[r] = fmaxf(mx[r], acc[t][r]);
#pragma unroll
    for (int off = 1; off < 16; off <<= 1)
#pragma unroll
      for (int r = 0; r < 4; ++r) mx[r] = fmaxf(mx[r], __shfl_xor(mx[r], off, 16));
    float ls[4] = {0.f, 0.f, 0.f, 0.f};
#pragma unroll
    for (int t = 0; t < 32; ++t)
#pragma unroll
      for (int r = 0; r < 4; ++r) {
        float p = __builtin_amdgcn_exp2f((acc[t][r] - mx[r]) * cexp);
        acc[t][r] = p;
        ls[r] += p;
      }
#pragma unroll
    for (int off = 1; off < 16; off <<= 1)
#pragma unroll
      for (int r = 0; r < 4; ++r) ls[r] += __shfl_xor(ls[r], off, 16);

    // PV in 4 chunks of 128 keys through the per-wave LDS buffer
    f32x4 o = {0.f, 0.f, 0.f, 0.f};
#pragma unroll
    for (int c = 0; c < 4; ++c) {
#pragma unroll
      for (int tt = 0; tt < 8; ++tt)
#pragma unroll
        for (int r = 0; r < 4; ++r)
          Pw[(q*4 + r)*136 + tt*16 + lq] =
              (short)(__float_as_uint(acc[c*8 + tt][r]) >> 16);
#pragma unroll
      for (int kk = 0; kk < 4; ++kk) {
        short8 ap = *(const short8*)&Pw[lq*136 + kk*32 + q*8];
        short8 bv = *(const short8*)&Vt[lq*520 + c*128 + kk*32 + q*8];
        o = __builtin_amdgcn_mfma_f32_16x16x32_bf16(ap, bv, o, 0, 0, 0);
      }
    }
#pragma unroll
    for (int r = 0; r < 4; ++r) {
      float ov = o[r] * __builtin_amdgcn_rcpf(ls[r]);
      O[(size_t)(qrow0 + q*4 + r)*128 + h*16 + lq] = f2bf(ov);
    }
  }
}

// ---------------- mean-pool + 2-layer classifier ----------------
__global__ __launch_bounds__(128) void pool_cls_kernel(const float* __restrict__ W,
                                                       float* __restrict__ outf) {
  int b = blockIdx.x, j = threadIdx.x;
  float s0 = 0.f, s1 = 0.f, s2 = 0.f, s3 = 0.f;
  const float* xb = W + OFF_X + b*512*128 + j;
  for (int ss = 0; ss < 128; ++ss) {
    s0 += xb[ss*128];
    s1 += xb[(128 + ss)*128];
    s2 += xb[(256 + ss)*128];
    s3 += xb[(384 + ss)*128];
  }
  __shared__ float pooled[128];
  __shared__ float hid[64];
  pooled[j] = (s0 + s1 + s2 + s3) * (1.f / 512.f);
  __syncthreads();
  if (j < 64) {
    float a = W[OFF_CB1 + j];
    for (int i = 0; i < 128; ++i) a += pooled[i] * W[OFF_CW1 + i*64 + j];
    hid[j] = fmaxf(a, 0.f);
  }
  __syncthreads();
  if (j < 5) {
    float a = W[OFF_CB2 + j];
    for (int i = 0; i < 64; ++i) a += hid[i] * W[OFF_CW2 + i*5 + j];
    outf[b*5 + j] = a;
  }
}

// ---------------- launch ----------------
extern "C" void kernel_launch(void* const* d_in, const int* in_sizes, int n_in,
                              void* d_out, int out_size, void* d_ws, size_t ws_size,
                              hipStream_t stream) {
  (void)in_sizes; (void)out_size; (void)ws_size;
  float* W = reinterpret_cast<float*>(d_ws);
  float* outf = reinterpret_cast<float*>(d_out);
  short* sdebf = (short*)(W + OFF_SDEBF);
  short* xbf   = (short*)(W + OFF_XBF);
  short* qkvbf = (short*)(W + OFF_QKVBF);
  short* obf   = (short*)(W + OFF_OBF);
  short* hbf   = (short*)(W + OFF_HBF);
  PtrPack pk;
  for (int i = 0; i < 45 && i < n_in; ++i) pk.p[i] = d_in[i];

  ingest_kernel<<<512, 256, 0, stream>>>(pk, W);
  prep_kernel<<<512, 256, 0, stream>>>(W);
  encoder_kernel<<<16384, 64, 0, stream>>>(W, outf);
  precompute_kernel<<<5110, 128, 0, stream>>>(W);
  sde_kernel<<<22, 256, 0, stream>>>(W, d_in[2], outf);

  // x = sde_features @ in_w + in_b  (fp32 master + bf16 mirror)
  gemm_ln64_kernel<<<256, 256, 0, stream>>>(sdebf, (short*)(W + OFF_INWT),
      W + OFF_INB, W + OFF_X, xbf, 64, nullptr, nullptr);
  for (int l = 0; l < 4; ++l) {
    gemm_bf16_kernel<<<dim3(128, 3), 256, 0, stream>>>(xbf,
        (short*)(W + OFF_WQKVT) + l*49152, W + OFF_BQKV + l*384,
        (float*)nullptr, qkvbf, 384, 128, 0);
    attn_kernel<<<256, 256, 0, stream>>>(qkvbf, obf);
    // wo-gemm with fused residual+LN1
    gemm_ln64_kernel<<<256, 256, 0, stream>>>(obf,
        (short*)(W + OFF_WOT) + l*16384, W + OFF_BO + l*128,
        W + OFF_X, xbf, 128, W + OFF_LN1G + l*128, W + OFF_LN1B + l*128);
    gemm_bf16_kernel<<<dim3(128, 4), 256, 0, stream>>>(xbf,
        (short*)(W + OFF_FW1T) + l*65536, W + OFF_FB1 + l*512,
        (float*)nullptr, hbf, 512, 128, 1);
    // fw2-gemm with fused residual+LN2
    gemm_ln64_kernel<<<256, 256, 0, stream>>>(hbf,
        (short*)(W + OFF_FW2T) + l*65536, W + OFF_FB2 + l*128,
        W + OFF_X, xbf, 512, W + OFF_LN2G + l*128, W + OFF_LN2B + l*128);
  }
  pool_cls_kernel<<<32, 128, 0, stream>>>(W, outf);
}